// Round 11
// baseline (366.835 us; speedup 1.0000x reference)
//
#include <hip/hip_runtime.h>
#include <hip/hip_cooperative_groups.h>
#include <math.h>

namespace cg = cooperative_groups;

#define NN 256
#define NE 4096
#define NC 128

using short8  = __attribute__((ext_vector_type(8))) short;
using short4v = __attribute__((ext_vector_type(4))) short;
using f32x4   = __attribute__((ext_vector_type(4))) float;

static __device__ __forceinline__ unsigned short f2bf(float x) {
    unsigned u = __float_as_uint(x);
    unsigned r = (u + 0x7FFF + ((u >> 16) & 1)) >> 16;   // RNE
    return (unsigned short)r;
}

static __device__ __forceinline__ float block_sum_256(float v, float* red4) {
    #pragma unroll
    for (int o = 32; o > 0; o >>= 1) v += __shfl_xor(v, o);
    __syncthreads();
    if ((threadIdx.x & 63) == 0) red4[threadIdx.x >> 6] = v;
    __syncthreads();
    return (red4[0] + red4[1]) + (red4[2] + red4[3]);
}

struct MegaArgs {
    const float* input; const int* src; const int* dst;
    const float *w1, *b1, *w2, *b2, *w3, *b3, *w4, *b4, *w5, *b5;
    const float *s1wl, *s1wr, *s1b, *s2wl, *s2wr, *s2b, *s3wl, *s3wr, *s3b;
    unsigned short *c1, *c2, *c3, *c4, *f1, *f2, *f3, *f4, *f5;
    float *P5, *ORG, *adj, *adjT, *s_soft, *s_softT, *T, *x1g, *lpart, *entp;
    float *out_main, *out_link, *out_ent, *out_nodes, *out_eb;
};

// ---- stage 0 items: weight frags f1-f5 + adj/adjT rows ----
static __device__ void prep_item(int b, const MegaArgs& a, int* icnt)
{
    int tid = threadIdx.x;
    if (b >= 478) {              // adj/adjT row build (LDS int counts)
        int* cntA = icnt; int* cntT = icnt + 256;
        const int n = b - 478;
        __syncthreads();
        cntA[tid] = 0; cntT[tid] = 0;
        __syncthreads();
        #pragma unroll
        for (int i = 0; i < 16; ++i) {
            int e = tid + i * 256;
            int s = a.src[e], d = a.dst[e];
            if (s == n) atomicAdd(&cntA[d], 1);
            if (d == n) atomicAdd(&cntT[s], 1);
        }
        __syncthreads();
        a.adj[n * NN + tid]  = (float)cntA[tid];
        a.adjT[n * NN + tid] = (float)cntT[tid];
        __syncthreads();
        return;
    }
    if (b == 477) {              // conv1 frags: 2 slots x 2 og x 64 lanes
        int lane = tid & 63, rest = tid >> 6;
        int g = rest & 1, slot = rest >> 1;
        int oc = g * 16 + (lane & 15);
        short8 v;
        #pragma unroll
        for (int j = 0; j < 8; ++j) {
            int k = (lane >> 4) * 8 + j;
            float wv = 0.f;
            if (slot == 0) {
                int tap = k >> 2, ch = k & 3;
                if (ch < 3) wv = a.w1[oc * 27 + ch * 9 + tap];
            } else {
                if (k < 3) wv = a.w1[oc * 27 + k * 9 + 8];
            }
            v[j] = (short)f2bf(wv);
        }
        *(short8*)&a.f1[(size_t)tid * 8] = v;
        return;
    }
    const float* w; unsigned short* f; int CIN, NG, NCH, base;
    if (b < 9)        { w = a.w2; f = a.f2; CIN = 32;  NG = 4;  NCH = 1; base = 0;   }
    else if (b < 45)  { w = a.w3; f = a.f3; CIN = 64;  NG = 8;  NCH = 2; base = 9;   }
    else if (b < 189) { w = a.w4; f = a.f4; CIN = 128; NG = 16; NCH = 4; base = 45;  }
    else              { w = a.w5; f = a.f5; CIN = 256; NG = 16; NCH = 8; base = 189; }
    int idx = (b - base) * 256 + tid;
    int lane = idx & 63, rest = idx >> 6;
    int c = rest % NCH; rest /= NCH;
    int g = rest % NG;  int t = rest / NG;
    if (t >= 9) return;
    int oc = g * 16 + (lane & 15);
    int cin0 = c * 32 + (lane >> 4) * 8;
    short8 v;
    #pragma unroll
    for (int j = 0; j < 8; ++j) {
        v[j] = (short)f2bf(w[((size_t)oc * CIN + cin0 + j) * 9 + t]);
    }
    *(short8*)&f[(size_t)idx * 8] = v;
}

// ---- conv1 tile: f32 3x512x512 -> pooled bf16 ch-last [256][256][32]; 16x16 tile ----
static __device__ void conv1_tile(int bx, int by, const MegaArgs& a, unsigned short* ldsb)
{
    constexpr int Hc = 512;
    const int tid = threadIdx.x;
    const int lane = tid & 63, wid = tid >> 6;
    const int col = lane & 15, kgl = lane >> 4;
    const int X0 = bx * 16, Y0 = by * 16;
    __syncthreads();                      // LDS reuse guard
    for (int i = tid; i < 324; i += 256) {
        int hy = i / 18, hx = i - hy * 18;
        int gy = Y0 + hy - 1, gx = X0 + hx - 1;
        float v0 = 0.f, v1 = 0.f, v2 = 0.f;
        if (gy >= 0 && gy < Hc && gx >= 0 && gx < Hc) {
            v0 = a.input[0 * 262144 + gy * 512 + gx];
            v1 = a.input[1 * 262144 + gy * 512 + gx];
            v2 = a.input[2 * 262144 + gy * 512 + gx];
        }
        uint2 uu;
        uu.x = f2bf(v0) | ((unsigned)f2bf(v1) << 16);
        uu.y = f2bf(v2);
        *(uint2*)&ldsb[(size_t)i * 4] = uu;
    }
    short8 af[2][2];
    #pragma unroll
    for (int slot = 0; slot < 2; ++slot) {
        #pragma unroll
        for (int g = 0; g < 2; ++g) {
            af[slot][g] = *(const short8*)&a.f1[((size_t)((slot * 2 + g) * 64 + lane)) * 8];
        }
    }
    __syncthreads();
    f32x4 acc[2][4];
    #pragma unroll
    for (int g = 0; g < 2; ++g) {
        #pragma unroll
        for (int r = 0; r < 4; ++r) acc[g][r] = {0.f, 0.f, 0.f, 0.f};
    }
    const int t0 = 2 * kgl, t1 = 2 * kgl + 1;
    const int dy0 = t0 / 3, dx0 = t0 % 3, dy1 = t1 / 3, dx1 = t1 % 3;
    #pragma unroll
    for (int r = 0; r < 4; ++r) {
        const int py = wid * 4 + r;
        short4v lo = *(const short4v*)&ldsb[((py + dy0) * 18 + col + dx0) * 4];
        short4v hi = *(const short4v*)&ldsb[((py + dy1) * 18 + col + dx1) * 4];
        short8 bf0 = __builtin_shufflevector(lo, hi, 0, 1, 2, 3, 4, 5, 6, 7);
        short4v z4 = {0, 0, 0, 0};
        short4v t8 = z4;
        if (kgl == 0) t8 = *(const short4v*)&ldsb[((py + 2) * 18 + col + 2) * 4];
        short8 bf1 = __builtin_shufflevector(t8, z4, 0, 1, 2, 3, 4, 5, 6, 7);
        #pragma unroll
        for (int g = 0; g < 2; ++g) {
            acc[g][r] = __builtin_amdgcn_mfma_f32_16x16x32_bf16(af[0][g], bf0, acc[g][r], 0, 0, 0);
            acc[g][r] = __builtin_amdgcn_mfma_f32_16x16x32_bf16(af[1][g], bf1, acc[g][r], 0, 0, 0);
        }
    }
    #pragma unroll
    for (int g = 0; g < 2; ++g) {
        const int oc = g * 16 + kgl * 4;
        const float4 bb = *(const float4*)&a.b1[oc];
        const float bbv[4] = {bb.x, bb.y, bb.z, bb.w};
        #pragma unroll
        for (int pr = 0; pr < 2; ++pr) {
            float vv[4];
            #pragma unroll
            for (int q = 0; q < 4; ++q) {
                float v = fmaxf(acc[g][2 * pr][q], acc[g][2 * pr + 1][q]);
                v = fmaxf(v, __shfl_xor(v, 1));
                vv[q] = fmaxf(v + bbv[q], 0.f);
            }
            if (!(col & 1)) {
                unsigned u0 = f2bf(vv[0]) | ((unsigned)f2bf(vv[1]) << 16);
                unsigned u1 = f2bf(vv[2]) | ((unsigned)f2bf(vv[3]) << 16);
                const int pry = Y0 / 2 + wid * 2 + pr;
                const int prx = X0 / 2 + (col >> 1);
                uint2 uu; uu.x = u0; uu.y = u1;
                *(uint2*)&a.c1[((size_t)(pry * 256 + prx)) * 32 + oc] = uu;
            }
        }
    }
}

// ---- conv tile (convs 2-5), async dbuf staging ----
template<int CIN, int COUT, int Hc, int OCB, int CSPLIT>
static __device__ void conv_tile(int bx, int by, int bz,
    const unsigned short* __restrict__ in, const unsigned short* __restrict__ wfrag,
    const float* __restrict__ bias, void* __restrict__ outv, unsigned short* ldsb)
{
    constexpr int TR = 8;
    constexpr int NOG = OCB / 16;
    constexpr int NG  = COUT / 16;
    constexpr int NCHT = CIN / 32;
    constexpr int NCH = NCHT / CSPLIT;
    constexpr int RPW = 2;
    constexpr int ITEMS = (TR + 2) * 18 * 4;   // 720
    constexpr int NIT = 3;
    const int tid = threadIdx.x;
    const int lane = tid & 63, wid = tid >> 6;
    const int col = lane & 15, kgl = lane >> 4;
    const int X0 = bx * 16, Y0 = by * TR;
    const int ob = bz / CSPLIT, cs = bz % CSPLIT;

    int ioff[NIT]; bool ival[NIT]; int loff[NIT];
    #pragma unroll
    for (int it = 0; it < NIT; ++it) {
        int i = tid + it * 256;
        int kg = i & 3, rem = i >> 2;
        int hx = rem % 18, hy = rem / 18;
        int gy = Y0 + hy - 1, gx = X0 + hx - 1;
        ival[it] = (i < ITEMS) && gy >= 0 && gy < Hc && gx >= 0 && gx < Hc;
        ioff[it] = (gy * Hc + gx) * CIN + kg * 8;
        loff[it] = ((hy * 4 + kg) * 18 + hx) * 8;
    }
    short8 sreg[NIT];
    auto sload = [&](int ca) {
        #pragma unroll
        for (int it = 0; it < NIT; ++it) {
            short8 v = {0, 0, 0, 0, 0, 0, 0, 0};
            if (ival[it]) v = *(const short8*)&in[ioff[it] + ca * 32];
            sreg[it] = v;
        }
    };
    auto swrite = [&](int buf) {
        #pragma unroll
        for (int it = 0; it < NIT; ++it) {
            if (tid + it * 256 < ITEMS) *(short8*)&ldsb[buf * (ITEMS * 8) + loff[it]] = sreg[it];
        }
    };

    f32x4 acc[NOG][RPW];
    #pragma unroll
    for (int g = 0; g < NOG; ++g) {
        #pragma unroll
        for (int r = 0; r < RPW; ++r) acc[g][r] = {0.f, 0.f, 0.f, 0.f};
    }

    __syncthreads();                       // LDS reuse guard across tiles
    sload(cs * NCH);
    swrite(0);
    __syncthreads();
    for (int cc = 0; cc < NCH; ++cc) {
        const int ca = cs * NCH + cc;
        if (cc + 1 < NCH) sload(ca + 1);
        const unsigned short* L = &ldsb[(cc & 1) * (ITEMS * 8)];
        #pragma unroll
        for (int t = 0; t < 9; ++t) {
            const int ky = t / 3, kx = t % 3;
            short8 af[NOG];
            #pragma unroll
            for (int g = 0; g < NOG; ++g) {
                af[g] = *(const short8*)&wfrag[((((size_t)t * NG + ob * NOG + g) * NCHT + ca) * 64 + lane) * 8];
            }
            #pragma unroll
            for (int r = 0; r < RPW; ++r) {
                const int py = wid * RPW + r;
                short8 bf = *(const short8*)&L[(((py + ky) * 4 + kgl) * 18 + col + kx) * 8];
                #pragma unroll
                for (int g = 0; g < NOG; ++g) {
                    acc[g][r] = __builtin_amdgcn_mfma_f32_16x16x32_bf16(af[g], bf, acc[g][r], 0, 0, 0);
                }
            }
        }
        if (cc + 1 < NCH) { swrite((cc + 1) & 1); __syncthreads(); }
    }

    if constexpr (CSPLIT == 1) {
        constexpr int Wp = Hc / 2;
        unsigned short* outp = (unsigned short*)outv;
        #pragma unroll
        for (int g = 0; g < NOG; ++g) {
            const int oc = (ob * NOG + g) * 16 + kgl * 4;
            const float4 bb = *(const float4*)&bias[oc];
            const float bbv[4] = {bb.x, bb.y, bb.z, bb.w};
            float vv[4];
            #pragma unroll
            for (int q = 0; q < 4; ++q) {
                float v = fmaxf(acc[g][0][q], acc[g][1][q]);
                v = fmaxf(v, __shfl_xor(v, 1));
                vv[q] = fmaxf(v + bbv[q], 0.f);
            }
            if (!(col & 1)) {
                unsigned u0 = f2bf(vv[0]) | ((unsigned)f2bf(vv[1]) << 16);
                unsigned u1 = f2bf(vv[2]) | ((unsigned)f2bf(vv[3]) << 16);
                const int pry = Y0 / 2 + wid;
                const int prx = X0 / 2 + (col >> 1);
                uint2 uu; uu.x = u0; uu.y = u1;
                *(uint2*)&outp[((size_t)(pry * Wp + prx)) * COUT + oc] = uu;
            }
        }
    } else {
        float* po = (float*)outv;
        #pragma unroll
        for (int g = 0; g < NOG; ++g) {
            #pragma unroll
            for (int r = 0; r < RPW; ++r) {
                const int gy = Y0 + wid * RPW + r;
                #pragma unroll
                for (int q = 0; q < 4; ++q) {
                    const int oc = (ob * NOG + g) * 16 + kgl * 4 + q;
                    po[((size_t)(cs * COUT + oc) * Hc + gy) * Hc + X0 + col] = acc[g][r][q];
                }
            }
        }
    }
}

// ---- finalize item: 256 elems each ----
static __device__ void finalize_item(int b, const MegaArgs& a)
{
    constexpr int HP = 16, H = 32, CS = 2, COUT = 256;
    int idx = b * 256 + threadIdx.x;
    int x = idx & (HP - 1); int rest = idx / HP;
    int y = rest & (HP - 1); int oc = rest / HP;
    float v00 = 0.f, v01 = 0.f, v10 = 0.f, v11 = 0.f;
    #pragma unroll
    for (int cs = 0; cs < CS; ++cs) {
        const float* p = a.P5 + ((size_t)(cs * COUT + oc) * H + 2 * y) * H + 2 * x;
        v00 += p[0]; v01 += p[1]; v10 += p[H]; v11 += p[H + 1];
    }
    float m = fmaxf(fmaxf(v00, v01), fmaxf(v10, v11)) + a.b5[oc];
    a.ORG[idx] = fmaxf(m, 0.f);
}

// ---- tail tiles ----
static __device__ void node_tile(int n, const MegaArgs& a, float* sf)
{
    int t = threadIdx.x;
    float* rowT = sf; float* orgn = sf + 256; float* aggn = sf + 512;
    float* red = sf + 768; float* sm = sf + 1024; float* red4 = sf + 1152;
    __syncthreads();
    float rT = a.adjT[n * 256 + t];
    rowT[t] = rT; orgn[t] = a.ORG[n * 256 + t];
    __syncthreads();
    float cnt = block_sum_256(rT, red4);
    float a0 = 0.f, a1 = 0.f, a2 = 0.f, a3 = 0.f;
    #pragma unroll 8
    for (int s = 0; s < 256; s += 4) {
        a0 = fmaf(rowT[s + 0], a.ORG[(s + 0) * 256 + t], a0);
        a1 = fmaf(rowT[s + 1], a.ORG[(s + 1) * 256 + t], a1);
        a2 = fmaf(rowT[s + 2], a.ORG[(s + 2) * 256 + t], a2);
        a3 = fmaf(rowT[s + 3], a.ORG[(s + 3) * 256 + t], a3);
    }
    float acc = (a0 + a1) + (a2 + a3);
    float aggv = (cnt > 0.f) ? acc / cnt : 0.f;
    aggn[t] = aggv;
    float orgv = orgn[t];
    float x10 = block_sum_256(aggv * a.s1wl[2 * t] + orgv * a.s1wr[2 * t], red4) + a.s1b[0];
    float x11 = block_sum_256(aggv * a.s1wl[2 * t + 1] + orgv * a.s1wr[2 * t + 1], red4) + a.s1b[1];
    if (t == 0) { a.x1g[n * 2 + 0] = x10; a.x1g[n * 2 + 1] = x11; }
    int p = t & 127, h = t >> 7;
    float b0 = 0.f, b1 = 0.f, b2 = 0.f, b3 = 0.f;
    #pragma unroll 8
    for (int k = h * 128; k < h * 128 + 128; k += 2) {
        b0 = fmaf(aggn[k],     a.s2wl[k * NC + p],       b0);
        b1 = fmaf(orgn[k],     a.s2wr[k * NC + p],       b1);
        b2 = fmaf(aggn[k + 1], a.s2wl[(k + 1) * NC + p], b2);
        b3 = fmaf(orgn[k + 1], a.s2wr[(k + 1) * NC + p], b3);
    }
    red[t] = (b0 + b1) + (b2 + b3);
    __syncthreads();
    if (t < 128) sm[p] = red[t] + red[t + 128] + a.s2b[p];
    __syncthreads();
    if (t < 128) red[t] = sm[t];
    __syncthreads();
    for (int s = 64; s > 0; s >>= 1) { if (t < s) red[t] = fmaxf(red[t], red[t + s]); __syncthreads(); }
    float mx = red[0];
    __syncthreads();
    float e = 0.f;
    if (t < 128) { e = expf(sm[t] - mx); red[t] = e; } else { red[t] = 0.f; }
    __syncthreads();
    for (int s = 64; s > 0; s >>= 1) { if (t < s) red[t] += red[t + s]; __syncthreads(); }
    float denom = red[0];
    float q = e / denom;
    if (t < 128) {
        a.s_soft[n * NC + t] = q;
        a.s_softT[t * 256 + n] = q;
    }
    float ev = (t < 128) ? -q * logf(q + 1e-15f) : 0.f;
    float esum = block_sum_256(ev, red4);
    if (t == 0) a.entp[n] = esum;
}

static __device__ void row_tile(int i, const MegaArgs& a, float* sf)
{
    int j = threadIdx.x;
    float* si = sf; float* adjrow = sf + 128; float* tbuf = sf + 384; float* red4 = sf + 640;
    __syncthreads();
    adjrow[j] = a.adj[i * 256 + j];
    if (j < NC) si[j] = a.s_soft[i * NC + j];
    __syncthreads();
    float d0 = 0.f, d1 = 0.f, d2 = 0.f, d3 = 0.f;
    #pragma unroll 8
    for (int k = 0; k < NC; k += 4) {
        d0 = fmaf(si[k + 0], a.s_softT[(k + 0) * 256 + j], d0);
        d1 = fmaf(si[k + 1], a.s_softT[(k + 1) * 256 + j], d1);
        d2 = fmaf(si[k + 2], a.s_softT[(k + 2) * 256 + j], d2);
        d3 = fmaf(si[k + 3], a.s_softT[(k + 3) * 256 + j], d3);
    }
    float dot = (d0 + d1) + (d2 + d3);
    float dd = adjrow[j] - dot;
    float lsum = block_sum_256(dd * dd, red4);
    if (j == 0) a.lpart[i] = lsum;
    int p = j & 127, h = j >> 7;
    float a0 = 0.f, a1 = 0.f;
    #pragma unroll 8
    for (int k = h * 128; k < h * 128 + 128; k += 2) {
        a0 = fmaf(adjrow[k],     a.s_soft[k * NC + p],       a0);
        a1 = fmaf(adjrow[k + 1], a.s_soft[(k + 1) * NC + p], a1);
    }
    tbuf[j] = a0 + a1;
    __syncthreads();
    if (j < 128) a.T[i * NC + j] = tbuf[j] + tbuf[j + 128];
}

static __device__ void cluster_tile(int c, const MegaArgs& a, float* sf)
{
    int t = threadIdx.x;
    float* colc = sf; float* red = sf + 256; float* ap = sf + 512; float* red4 = sf + 640;
    __syncthreads();
    colc[t] = a.s_softT[c * 256 + t];
    __syncthreads();
    int p = t & 127, h = t >> 7;
    float a0 = 0.f, a1 = 0.f;
    #pragma unroll 8
    for (int n = h * 128; n < h * 128 + 128; n += 2) {
        a0 = fmaf(colc[n],     a.T[n * NC + p],       a0);
        a1 = fmaf(colc[n + 1], a.T[(n + 1) * NC + p], a1);
    }
    red[t] = a0 + a1;
    __syncthreads();
    if (t < 128) ap[t] = red[t] + red[t + 128];
    __syncthreads();
    if (t < 128) red[t] = ap[t];
    __syncthreads();
    for (int s = 64; s > 0; s >>= 1) { if (t < s) red[t] = fmaxf(red[t], red[t + s]); __syncthreads(); }
    float mx = red[0];
    if (t < 128) a.out_eb[c * NC + t] = (ap[t] == mx) ? 1.f : 0.f;
    float n0 = tanhf(block_sum_256(colc[t] * a.x1g[t * 2 + 0], red4));
    float n1 = tanhf(block_sum_256(colc[t] * a.x1g[t * 2 + 1], red4));
    if (t == 0) { a.out_nodes[c * 2 + 0] = n0; a.out_nodes[c * 2 + 1] = n1; }
}

static __device__ void final_tile(const MegaArgs& a, float* sf)
{
    int t = threadIdx.x;
    float* red4 = sf;
    __syncthreads();
    float ls = block_sum_256(a.lpart[t], red4);
    if (t == 0) a.out_link[0] = sqrtf(ls) / (float)(NN * NN);
    float es = block_sum_256(a.entp[t], red4);
    if (t == 0) a.out_ent[0] = es / (float)NN;
    if (t < NC) {
        int j = t;
        float i0 = 0.f, i1 = 0.f, a00 = 0.f, a01 = 0.f, a10 = 0.f, a11 = 0.f;
        #pragma unroll 8
        for (int i2 = 0; i2 < NC; i2 += 2) {
            float e0 = a.out_eb[i2 * NC + j];
            float e1 = a.out_eb[(i2 + 1) * NC + j];
            i0 += e0; i1 += e1;
            a00 = fmaf(e0, a.out_nodes[i2 * 2 + 0], a00);
            a01 = fmaf(e0, a.out_nodes[i2 * 2 + 1], a01);
            a10 = fmaf(e1, a.out_nodes[(i2 + 1) * 2 + 0], a10);
            a11 = fmaf(e1, a.out_nodes[(i2 + 1) * 2 + 1], a11);
        }
        float indeg = i0 + i1;
        float a0 = a00 + a10, a1 = a01 + a11;
        float inv = (indeg > 0.f) ? 1.f / fmaxf(indeg, 1.f) : 0.f;
        float g0 = a0 * inv, g1 = a1 * inv;
        float n0 = a.out_nodes[j * 2 + 0], n1 = a.out_nodes[j * 2 + 1];
        a.out_main[j * 2 + 0] = g0 * a.s3wl[0] + g1 * a.s3wl[2] + a.s3b[0] + n0 * a.s3wr[0] + n1 * a.s3wr[2];
        a.out_main[j * 2 + 1] = g0 * a.s3wl[1] + g1 * a.s3wl[3] + a.s3b[1] + n0 * a.s3wr[1] + n1 * a.s3wr[3];
    }
}

// ================= the cooperative mega-kernel =================
__global__ __launch_bounds__(256) void mega_kernel(MegaArgs a)
{
    cg::grid_group grid = cg::this_grid();
    __shared__ __align__(16) unsigned char smem_[23040];
    unsigned short* ldsb = (unsigned short*)smem_;
    float* sf = (float*)smem_;
    const int nb = gridDim.x;

    for (int b = blockIdx.x; b < 734; b += nb) prep_item(b, a, (int*)smem_);
    grid.sync();
    for (int b = blockIdx.x; b < 1024; b += nb) conv1_tile(b & 31, b >> 5, a, ldsb);
    grid.sync();
    for (int b = blockIdx.x; b < 512; b += nb)
        conv_tile<32, 64, 256, 64, 1>(b & 15, b >> 4, 0, a.c1, a.f2, a.b2, a.c2, ldsb);
    grid.sync();
    for (int b = blockIdx.x; b < 256; b += nb)
        conv_tile<64, 128, 128, 64, 1>(b & 7, (b >> 3) & 15, b >> 7, a.c2, a.f3, a.b3, a.c3, ldsb);
    grid.sync();
    for (int b = blockIdx.x; b < 256; b += nb)
        conv_tile<128, 256, 64, 32, 1>(b & 3, (b >> 2) & 7, b >> 5, a.c3, a.f4, a.b4, a.c4, ldsb);
    grid.sync();
    for (int b = blockIdx.x; b < 256; b += nb)
        conv_tile<256, 256, 32, 16, 2>(b & 1, (b >> 1) & 3, b >> 3, a.c4, a.f5, a.b5, a.P5, ldsb);
    grid.sync();
    for (int b = blockIdx.x; b < 256; b += nb) finalize_item(b, a);
    grid.sync();
    for (int b = blockIdx.x; b < 256; b += nb) node_tile(b, a, sf);
    grid.sync();
    for (int b = blockIdx.x; b < 256; b += nb) row_tile(b, a, sf);
    grid.sync();
    for (int b = blockIdx.x; b < 128; b += nb) cluster_tile(b, a, sf);
    grid.sync();
    if (blockIdx.x == 0) final_tile(a, sf);
}

extern "C" void kernel_launch(void* const* d_in, const int* in_sizes, int n_in,
                              void* d_out, int out_size, void* d_ws, size_t ws_size,
                              hipStream_t stream)
{
    const int* eidx = (const int*)d_in[1];
    float* ws = (float*)d_ws;
    float* fout = (float*)d_out;

    MegaArgs a;
    a.input = (const float*)d_in[0];
    a.src = eidx; a.dst = eidx + NE;
    a.w1 = (const float*)d_in[2];  a.b1 = (const float*)d_in[3];
    a.w2 = (const float*)d_in[4];  a.b2 = (const float*)d_in[5];
    a.w3 = (const float*)d_in[6];  a.b3 = (const float*)d_in[7];
    a.w4 = (const float*)d_in[8];  a.b4 = (const float*)d_in[9];
    a.w5 = (const float*)d_in[10]; a.b5 = (const float*)d_in[11];
    a.s1wl = (const float*)d_in[12]; a.s1wr = (const float*)d_in[13]; a.s1b = (const float*)d_in[14];
    a.s2wl = (const float*)d_in[15]; a.s2wr = (const float*)d_in[16]; a.s2b = (const float*)d_in[17];
    a.s3wl = (const float*)d_in[18]; a.s3wr = (const float*)d_in[19]; a.s3b = (const float*)d_in[20];

    a.c1 = (unsigned short*)(ws);
    a.c2 = (unsigned short*)(ws + 1048576);
    a.c3 = (unsigned short*)(ws);
    a.c4 = (unsigned short*)(ws + 1048576);
    a.P5 = ws;                       // 2*256*32*32 f32 (c3 dead by then)
    a.ORG = ws + 1179648;
    a.f1 = (unsigned short*)(ws + 1572864);
    a.f2 = (unsigned short*)(ws + 1573888);
    a.f3 = (unsigned short*)(ws + 1583104);
    a.f4 = (unsigned short*)(ws + 1619968);
    a.f5 = (unsigned short*)(ws + 1767424);
    a.adj = ws + 2062336;
    a.adjT = ws + 2127872;
    a.s_soft = ws + 2193408;
    a.T = ws + 2226176;
    a.x1g = ws + 2258944;
    a.lpart = ws + 2259456;
    a.entp = ws + 2259712;
    a.s_softT = ws + 2259968;        // 128*256

    a.out_main = fout;
    a.out_link = fout + 256;
    a.out_ent = fout + 257;
    a.out_nodes = fout + 258;
    a.out_eb = fout + 514;

    void* kargs[] = { (void*)&a };
    hipLaunchCooperativeKernel((const void*)mega_kernel, dim3(256), dim3(256),
                               kargs, 0, stream);
}

// Round 12
// 104.922 us; speedup vs baseline: 3.4963x; 3.4963x over previous
//
#include <hip/hip_runtime.h>
#include <math.h>

#define NN 256
#define NE 4096
#define NC 128

using short8  = __attribute__((ext_vector_type(8))) short;
using short4v = __attribute__((ext_vector_type(4))) short;
using f32x4   = __attribute__((ext_vector_type(4))) float;

static __device__ __forceinline__ unsigned short f2bf(float x) {
    unsigned u = __float_as_uint(x);
    unsigned r = (u + 0x7FFF + ((u >> 16) & 1)) >> 16;   // RNE
    return (unsigned short)r;
}

static __device__ __forceinline__ float block_sum_256(float v, float* red4) {
    #pragma unroll
    for (int o = 32; o > 0; o >>= 1) v += __shfl_xor(v, o);
    __syncthreads();
    if ((threadIdx.x & 63) == 0) red4[threadIdx.x >> 6] = v;
    __syncthreads();
    return (red4[0] + red4[1]) + (red4[2] + red4[3]);
}

// ============ mega dispatch 1: conv1(inline frags) + f2-f5 prep + adj/adjT rows ============
// blocks [0,2048): conv1 MFMA tiles; [2048,2525): wfrag f2-f5; [2525,2781): adj rows
__global__ __launch_bounds__(256) void mega1_kernel(
    const float* __restrict__ in, const float* __restrict__ w1, const float* __restrict__ bias1,
    unsigned short* __restrict__ c1out,
    const float* __restrict__ w2, const float* __restrict__ w3, const float* __restrict__ w4,
    const float* __restrict__ w5,
    unsigned short* __restrict__ f2, unsigned short* __restrict__ f3,
    unsigned short* __restrict__ f4, unsigned short* __restrict__ f5,
    const int* __restrict__ src, const int* __restrict__ dst,
    float* __restrict__ adj, float* __restrict__ adjT)
{
    const int bid = blockIdx.x;
    const int tid = threadIdx.x;
    if (bid >= 2525) {           // ---- adj/adjT row build (atomic-free to global, LDS ints) ----
        __shared__ int cntA[256], cntT[256];
        const int n = bid - 2525;
        cntA[tid] = 0; cntT[tid] = 0;
        __syncthreads();
        #pragma unroll
        for (int i = 0; i < 16; ++i) {
            int e = tid + i * 256;
            int s = src[e], d = dst[e];
            if (s == n) atomicAdd(&cntA[d], 1);
            if (d == n) atomicAdd(&cntT[s], 1);
        }
        __syncthreads();
        adj[n * NN + tid]  = (float)cntA[tid];
        adjT[n * NN + tid] = (float)cntT[tid];
        return;
    }
    if (bid >= 2048) {           // ---- wfrag prep for convs 2-5 ----
        int b = bid - 2048;
        const float* w; unsigned short* f; int CIN, NG, NCH, base;
        if (b < 9)        { w = w2; f = f2; CIN = 32;  NG = 4;  NCH = 1; base = 0;   }
        else if (b < 45)  { w = w3; f = f3; CIN = 64;  NG = 8;  NCH = 2; base = 9;   }
        else if (b < 189) { w = w4; f = f4; CIN = 128; NG = 16; NCH = 4; base = 45;  }
        else              { w = w5; f = f5; CIN = 256; NG = 16; NCH = 8; base = 189; }
        int idx = (b - base) * 256 + tid;
        int lane = idx & 63, rest = idx >> 6;
        int c = rest % NCH; rest /= NCH;
        int g = rest % NG;  int t = rest / NG;
        if (t >= 9) return;
        int oc = g * 16 + (lane & 15);
        int cin0 = c * 32 + (lane >> 4) * 8;
        short8 v;
        #pragma unroll
        for (int j = 0; j < 8; ++j) {
            v[j] = (short)f2bf(w[((size_t)oc * CIN + cin0 + j) * 9 + t]);
        }
        *(short8*)&f[(size_t)idx * 8] = v;
        return;
    }
    // ---- conv1: f32 NCHW 3x512x512 -> pooled bf16 ch-last [256][256][32] ----
    constexpr int Hc = 512;
    const int lane = tid & 63, wid = tid >> 6;
    const int col = lane & 15, kgl = lane >> 4;
    const int X0 = (bid & 31) * 16, Y0 = (bid >> 5) * 8;
    __shared__ __align__(16) unsigned short lds[10][18][4];
    if (tid < 180) {
        int hy = tid / 18, hx = tid - hy * 18;
        int gy = Y0 + hy - 1, gx = X0 + hx - 1;
        float v0 = 0.f, v1 = 0.f, v2 = 0.f;
        if (gy >= 0 && gy < Hc && gx >= 0 && gx < Hc) {
            v0 = in[0 * 262144 + gy * 512 + gx];
            v1 = in[1 * 262144 + gy * 512 + gx];
            v2 = in[2 * 262144 + gy * 512 + gx];
        }
        uint2 uu;
        uu.x = f2bf(v0) | ((unsigned)f2bf(v1) << 16);
        uu.y = f2bf(v2);
        *(uint2*)&lds[hy][hx][0] = uu;
    }
    // inline A-frags from w1 (slot0: k=tap*4+ch taps 0-7; slot1: k=ch tap 8)
    short8 af[2][2];
    #pragma unroll
    for (int slot = 0; slot < 2; ++slot) {
        #pragma unroll
        for (int g = 0; g < 2; ++g) {
            int oc = g * 16 + (lane & 15);
            short8 v;
            #pragma unroll
            for (int j = 0; j < 8; ++j) {
                int k = (lane >> 4) * 8 + j;
                float wv = 0.f;
                if (slot == 0) {
                    int tap = k >> 2, ch = k & 3;
                    if (ch < 3) wv = w1[oc * 27 + ch * 9 + tap];
                } else {
                    if (k < 3) wv = w1[oc * 27 + k * 9 + 8];
                }
                v[j] = (short)f2bf(wv);
            }
            af[slot][g] = v;
        }
    }
    __syncthreads();
    f32x4 acc[2][2];
    #pragma unroll
    for (int g = 0; g < 2; ++g) {
        #pragma unroll
        for (int r = 0; r < 2; ++r) acc[g][r] = {0.f, 0.f, 0.f, 0.f};
    }
    const int t0 = 2 * kgl, t1 = 2 * kgl + 1;
    const int dy0 = t0 / 3, dx0 = t0 % 3, dy1 = t1 / 3, dx1 = t1 % 3;
    #pragma unroll
    for (int r = 0; r < 2; ++r) {
        const int py = wid * 2 + r;
        short4v lo = *(const short4v*)&lds[py + dy0][col + dx0][0];
        short4v hi = *(const short4v*)&lds[py + dy1][col + dx1][0];
        short8 bf0 = __builtin_shufflevector(lo, hi, 0, 1, 2, 3, 4, 5, 6, 7);
        short4v z4 = {0, 0, 0, 0};
        short4v t8 = z4;
        if (kgl == 0) t8 = *(const short4v*)&lds[py + 2][col + 2][0];
        short8 bf1 = __builtin_shufflevector(t8, z4, 0, 1, 2, 3, 4, 5, 6, 7);
        #pragma unroll
        for (int g = 0; g < 2; ++g) {
            acc[g][r] = __builtin_amdgcn_mfma_f32_16x16x32_bf16(af[0][g], bf0, acc[g][r], 0, 0, 0);
            acc[g][r] = __builtin_amdgcn_mfma_f32_16x16x32_bf16(af[1][g], bf1, acc[g][r], 0, 0, 0);
        }
    }
    #pragma unroll
    for (int g = 0; g < 2; ++g) {
        const int oc = g * 16 + kgl * 4;
        const float4 bb = *(const float4*)&bias1[oc];
        const float bbv[4] = {bb.x, bb.y, bb.z, bb.w};
        float vv[4];
        #pragma unroll
        for (int q = 0; q < 4; ++q) {
            float v = fmaxf(acc[g][0][q], acc[g][1][q]);
            v = fmaxf(v, __shfl_xor(v, 1));
            vv[q] = fmaxf(v + bbv[q], 0.f);
        }
        if (!(col & 1)) {
            unsigned u0 = f2bf(vv[0]) | ((unsigned)f2bf(vv[1]) << 16);
            unsigned u1 = f2bf(vv[2]) | ((unsigned)f2bf(vv[3]) << 16);
            const int pry = Y0 / 2 + wid;
            const int prx = X0 / 2 + (col >> 1);
            uint2 uu; uu.x = u0; uu.y = u1;
            *(uint2*)&c1out[((size_t)(pry * 256 + prx)) * 32 + oc] = uu;
        }
    }
}

// ============ MFMA conv (convs 2-5), async dbuf staging ============
// CSPLIT==1: fused bias+relu+pool2x2 -> bf16 ch-last [Hc/2][Hc/2][COUT]
// CSPLIT>1 : raw f32 partial out [cs][COUT][Hc][Hc]
template<int CIN, int COUT, int Hc, int OCB, int CSPLIT>
__global__ __launch_bounds__(256) void conv_mfma(
    const unsigned short* __restrict__ in, const unsigned short* __restrict__ wfrag,
    const float* __restrict__ bias, void* __restrict__ outv)
{
    constexpr int TR = 8;
    constexpr int NOG = OCB / 16;
    constexpr int NG  = COUT / 16;
    constexpr int NCHT = CIN / 32;
    constexpr int NCH = NCHT / CSPLIT;
    constexpr int RPW = 2;
    constexpr int ITEMS = (TR + 2) * 18 * 4;   // 720
    constexpr int NIT = 3;
    const int tid = threadIdx.x;
    const int lane = tid & 63, wid = tid >> 6;
    const int col = lane & 15, kgl = lane >> 4;
    const int X0 = blockIdx.x * 16, Y0 = blockIdx.y * TR;
    const int ob = blockIdx.z / CSPLIT, cs = blockIdx.z % CSPLIT;

    __shared__ __align__(16) unsigned short lds[2][ITEMS * 8];

    int ioff[NIT]; bool ival[NIT]; int loff[NIT];
    #pragma unroll
    for (int it = 0; it < NIT; ++it) {
        int i = tid + it * 256;
        int kg = i & 3, rem = i >> 2;
        int hx = rem % 18, hy = rem / 18;
        int gy = Y0 + hy - 1, gx = X0 + hx - 1;
        ival[it] = (i < ITEMS) && gy >= 0 && gy < Hc && gx >= 0 && gx < Hc;
        ioff[it] = (gy * Hc + gx) * CIN + kg * 8;
        loff[it] = ((hy * 4 + kg) * 18 + hx) * 8;
    }
    short8 sreg[NIT];
    auto sload = [&](int ca) {
        #pragma unroll
        for (int it = 0; it < NIT; ++it) {
            short8 v = {0, 0, 0, 0, 0, 0, 0, 0};
            if (ival[it]) v = *(const short8*)&in[ioff[it] + ca * 32];
            sreg[it] = v;
        }
    };
    auto swrite = [&](int buf) {
        #pragma unroll
        for (int it = 0; it < NIT; ++it) {
            if (tid + it * 256 < ITEMS) *(short8*)&lds[buf][loff[it]] = sreg[it];
        }
    };

    f32x4 acc[NOG][RPW];
    #pragma unroll
    for (int g = 0; g < NOG; ++g) {
        #pragma unroll
        for (int r = 0; r < RPW; ++r) acc[g][r] = {0.f, 0.f, 0.f, 0.f};
    }

    sload(cs * NCH);
    swrite(0);
    __syncthreads();
    for (int cc = 0; cc < NCH; ++cc) {
        const int ca = cs * NCH + cc;
        if (cc + 1 < NCH) sload(ca + 1);          // issue next chunk's loads early
        const unsigned short* L = &lds[cc & 1][0];
        #pragma unroll
        for (int t = 0; t < 9; ++t) {
            const int ky = t / 3, kx = t % 3;
            short8 af[NOG];
            #pragma unroll
            for (int g = 0; g < NOG; ++g) {
                af[g] = *(const short8*)&wfrag[((((size_t)t * NG + ob * NOG + g) * NCHT + ca) * 64 + lane) * 8];
            }
            #pragma unroll
            for (int r = 0; r < RPW; ++r) {
                const int py = wid * RPW + r;
                short8 bf = *(const short8*)&L[(((py + ky) * 4 + kgl) * 18 + col + kx) * 8];
                #pragma unroll
                for (int g = 0; g < NOG; ++g) {
                    acc[g][r] = __builtin_amdgcn_mfma_f32_16x16x32_bf16(af[g], bf, acc[g][r], 0, 0, 0);
                }
            }
        }
        if (cc + 1 < NCH) { swrite((cc + 1) & 1); __syncthreads(); }
    }

    if constexpr (CSPLIT == 1) {
        constexpr int Wp = Hc / 2;
        unsigned short* outp = (unsigned short*)outv;
        #pragma unroll
        for (int g = 0; g < NOG; ++g) {
            const int oc = (ob * NOG + g) * 16 + kgl * 4;
            const float4 bb = *(const float4*)&bias[oc];
            const float bbv[4] = {bb.x, bb.y, bb.z, bb.w};
            float vv[4];
            #pragma unroll
            for (int q = 0; q < 4; ++q) {
                float v = fmaxf(acc[g][0][q], acc[g][1][q]);
                v = fmaxf(v, __shfl_xor(v, 1));
                vv[q] = fmaxf(v + bbv[q], 0.f);
            }
            if (!(col & 1)) {
                unsigned u0 = f2bf(vv[0]) | ((unsigned)f2bf(vv[1]) << 16);
                unsigned u1 = f2bf(vv[2]) | ((unsigned)f2bf(vv[3]) << 16);
                const int pry = Y0 / 2 + wid;
                const int prx = X0 / 2 + (col >> 1);
                uint2 uu; uu.x = u0; uu.y = u1;
                *(uint2*)&outp[((size_t)(pry * Wp + prx)) * COUT + oc] = uu;
            }
        }
    } else {
        float* po = (float*)outv;
        #pragma unroll
        for (int g = 0; g < NOG; ++g) {
            #pragma unroll
            for (int r = 0; r < RPW; ++r) {
                const int gy = Y0 + wid * RPW + r;
                #pragma unroll
                for (int q = 0; q < 4; ++q) {
                    const int oc = (ob * NOG + g) * 16 + kgl * 4 + q;
                    po[((size_t)(cs * COUT + oc) * Hc + gy) * Hc + X0 + col] = acc[g][r][q];
                }
            }
        }
    }
}

// sum CS pre-pool f32 partials, add bias, relu, 2x2 maxpool -> f32 channel-major out
template<int COUT, int HP, int CS>
__global__ void finalize_pool(const float* __restrict__ partial, const float* __restrict__ bias,
                              float* __restrict__ out)
{
    int idx = blockIdx.x * 256 + threadIdx.x;
    if (idx >= COUT * HP * HP) return;
    constexpr int H = HP * 2;
    int x = idx & (HP - 1); int rest = idx / HP;
    int y = rest & (HP - 1); int oc = rest / HP;
    float v00 = 0.f, v01 = 0.f, v10 = 0.f, v11 = 0.f;
    #pragma unroll
    for (int cs = 0; cs < CS; ++cs) {
        const float* p = partial + ((size_t)(cs * COUT + oc) * H + 2 * y) * H + 2 * x;
        v00 += p[0]; v01 += p[1]; v10 += p[H]; v11 += p[H + 1];
    }
    float m = fmaxf(fmaxf(v00, v01), fmaxf(v10, v11)) + bias[oc];
    out[idx] = fmaxf(m, 0.f);
}

// ============ fused graph tail ============

__global__ __launch_bounds__(256) void node_fused_kernel(
    const float* __restrict__ adjT, const float* __restrict__ org,
    const float* __restrict__ s1wl, const float* __restrict__ s1wr, const float* __restrict__ s1b,
    const float* __restrict__ s2wl, const float* __restrict__ s2wr, const float* __restrict__ s2b,
    float* __restrict__ s_soft, float* __restrict__ s_softT,
    float* __restrict__ x1g, float* __restrict__ entp)
{
    int n = blockIdx.x, t = threadIdx.x;
    __shared__ float rowT[256], orgn[256], aggn[256], red[256], sm[128], red4[4];
    float rT = adjT[n * 256 + t];
    rowT[t] = rT; orgn[t] = org[n * 256 + t];
    __syncthreads();
    float cnt = block_sum_256(rT, red4);
    float a0 = 0.f, a1 = 0.f, a2 = 0.f, a3 = 0.f;
    #pragma unroll 8
    for (int s = 0; s < 256; s += 4) {
        a0 = fmaf(rowT[s + 0], org[(s + 0) * 256 + t], a0);
        a1 = fmaf(rowT[s + 1], org[(s + 1) * 256 + t], a1);
        a2 = fmaf(rowT[s + 2], org[(s + 2) * 256 + t], a2);
        a3 = fmaf(rowT[s + 3], org[(s + 3) * 256 + t], a3);
    }
    float acc = (a0 + a1) + (a2 + a3);
    float aggv = (cnt > 0.f) ? acc / cnt : 0.f;
    aggn[t] = aggv;
    float orgv = orgn[t];
    float x10 = block_sum_256(aggv * s1wl[2 * t] + orgv * s1wr[2 * t], red4) + s1b[0];
    float x11 = block_sum_256(aggv * s1wl[2 * t + 1] + orgv * s1wr[2 * t + 1], red4) + s1b[1];
    if (t == 0) { x1g[n * 2 + 0] = x10; x1g[n * 2 + 1] = x11; }
    int p = t & 127, h = t >> 7;
    float b0 = 0.f, b1 = 0.f, b2 = 0.f, b3 = 0.f;
    #pragma unroll 8
    for (int k = h * 128; k < h * 128 + 128; k += 2) {
        b0 = fmaf(aggn[k],     s2wl[k * NC + p],       b0);
        b1 = fmaf(orgn[k],     s2wr[k * NC + p],       b1);
        b2 = fmaf(aggn[k + 1], s2wl[(k + 1) * NC + p], b2);
        b3 = fmaf(orgn[k + 1], s2wr[(k + 1) * NC + p], b3);
    }
    red[t] = (b0 + b1) + (b2 + b3);
    __syncthreads();
    if (t < 128) sm[p] = red[t] + red[t + 128] + s2b[p];
    __syncthreads();
    if (t < 128) red[t] = sm[t];
    __syncthreads();
    for (int s = 64; s > 0; s >>= 1) { if (t < s) red[t] = fmaxf(red[t], red[t + s]); __syncthreads(); }
    float mx = red[0];
    __syncthreads();
    float e = 0.f;
    if (t < 128) { e = expf(sm[t] - mx); red[t] = e; } else { red[t] = 0.f; }
    __syncthreads();
    for (int s = 64; s > 0; s >>= 1) { if (t < s) red[t] += red[t + s]; __syncthreads(); }
    float denom = red[0];
    float q = e / denom;
    if (t < 128) {
        s_soft[n * NC + t] = q;
        s_softT[t * 256 + n] = q;
    }
    float ev = (t < 128) ? -q * logf(q + 1e-15f) : 0.f;
    float esum = block_sum_256(ev, red4);
    if (t == 0) entp[n] = esum;
}

__global__ __launch_bounds__(256) void row_fused_kernel(
    const float* __restrict__ adj, const float* __restrict__ s_soft,
    const float* __restrict__ s_softT, float* __restrict__ T, float* __restrict__ lpart)
{
    int i = blockIdx.x, j = threadIdx.x;
    __shared__ float si[NC], adjrow[256], tbuf[256], red4[4];
    adjrow[j] = adj[i * 256 + j];
    if (j < NC) si[j] = s_soft[i * NC + j];
    __syncthreads();
    float d0 = 0.f, d1 = 0.f, d2 = 0.f, d3 = 0.f;
    #pragma unroll 8
    for (int k = 0; k < NC; k += 4) {
        d0 = fmaf(si[k + 0], s_softT[(k + 0) * 256 + j], d0);
        d1 = fmaf(si[k + 1], s_softT[(k + 1) * 256 + j], d1);
        d2 = fmaf(si[k + 2], s_softT[(k + 2) * 256 + j], d2);
        d3 = fmaf(si[k + 3], s_softT[(k + 3) * 256 + j], d3);
    }
    float dot = (d0 + d1) + (d2 + d3);
    float dd = adjrow[j] - dot;
    float lsum = block_sum_256(dd * dd, red4);
    if (j == 0) lpart[i] = lsum;
    int p = j & 127, h = j >> 7;
    float a0 = 0.f, a1 = 0.f;
    #pragma unroll 8
    for (int k = h * 128; k < h * 128 + 128; k += 2) {
        a0 = fmaf(adjrow[k],     s_soft[k * NC + p],       a0);
        a1 = fmaf(adjrow[k + 1], s_soft[(k + 1) * NC + p], a1);
    }
    tbuf[j] = a0 + a1;
    __syncthreads();
    if (j < 128) T[i * NC + j] = tbuf[j] + tbuf[j + 128];
}

__global__ __launch_bounds__(256) void cluster_fused_kernel(
    const float* __restrict__ s_softT, const float* __restrict__ T, const float* __restrict__ x1g,
    float* __restrict__ eb_out, float* __restrict__ nodes_out)
{
    int c = blockIdx.x, t = threadIdx.x;
    __shared__ float colc[256], red[256], ap[NC], red4[4];
    colc[t] = s_softT[c * 256 + t];
    __syncthreads();
    int p = t & 127, h = t >> 7;
    float a0 = 0.f, a1 = 0.f;
    #pragma unroll 8
    for (int n = h * 128; n < h * 128 + 128; n += 2) {
        a0 = fmaf(colc[n],     T[n * NC + p],       a0);
        a1 = fmaf(colc[n + 1], T[(n + 1) * NC + p], a1);
    }
    red[t] = a0 + a1;
    __syncthreads();
    if (t < 128) ap[t] = red[t] + red[t + 128];
    __syncthreads();
    if (t < 128) red[t] = ap[t];
    __syncthreads();
    for (int s = 64; s > 0; s >>= 1) { if (t < s) red[t] = fmaxf(red[t], red[t + s]); __syncthreads(); }
    float mx = red[0];
    if (t < 128) eb_out[c * NC + t] = (ap[t] == mx) ? 1.f : 0.f;
    float n0 = tanhf(block_sum_256(colc[t] * x1g[t * 2 + 0], red4));
    float n1 = tanhf(block_sum_256(colc[t] * x1g[t * 2 + 1], red4));
    if (t == 0) { nodes_out[c * 2 + 0] = n0; nodes_out[c * 2 + 1] = n1; }
}

__global__ __launch_bounds__(256) void final_kernel(
    const float* __restrict__ lpart, const float* __restrict__ entp,
    const float* __restrict__ eb, const float* __restrict__ nodes,
    const float* __restrict__ wl, const float* __restrict__ wr, const float* __restrict__ b,
    float* __restrict__ out_main, float* __restrict__ out_link, float* __restrict__ out_ent)
{
    int t = threadIdx.x;
    __shared__ float red4[4];
    float ls = block_sum_256(lpart[t], red4);
    if (t == 0) out_link[0] = sqrtf(ls) / (float)(NN * NN);
    float es = block_sum_256(entp[t], red4);
    if (t == 0) out_ent[0] = es / (float)NN;
    if (t < NC) {
        int j = t;
        float i0 = 0.f, i1 = 0.f, a00 = 0.f, a01 = 0.f, a10 = 0.f, a11 = 0.f;
        #pragma unroll 8
        for (int i2 = 0; i2 < NC; i2 += 2) {
            float e0 = eb[i2 * NC + j];
            float e1 = eb[(i2 + 1) * NC + j];
            i0 += e0; i1 += e1;
            a00 = fmaf(e0, nodes[i2 * 2 + 0], a00);
            a01 = fmaf(e0, nodes[i2 * 2 + 1], a01);
            a10 = fmaf(e1, nodes[(i2 + 1) * 2 + 0], a10);
            a11 = fmaf(e1, nodes[(i2 + 1) * 2 + 1], a11);
        }
        float indeg = i0 + i1;
        float a0 = a00 + a10, a1 = a01 + a11;
        float inv = (indeg > 0.f) ? 1.f / fmaxf(indeg, 1.f) : 0.f;
        float g0 = a0 * inv, g1 = a1 * inv;
        float n0 = nodes[j * 2 + 0], n1 = nodes[j * 2 + 1];
        out_main[j * 2 + 0] = g0 * wl[0] + g1 * wl[2] + b[0] + n0 * wr[0] + n1 * wr[2];
        out_main[j * 2 + 1] = g0 * wl[1] + g1 * wl[3] + b[1] + n0 * wr[1] + n1 * wr[3];
    }
}

extern "C" void kernel_launch(void* const* d_in, const int* in_sizes, int n_in,
                              void* d_out, int out_size, void* d_ws, size_t ws_size,
                              hipStream_t stream)
{
    const float* input = (const float*)d_in[0];
    const int* eidx = (const int*)d_in[1];
    const int* src = eidx;
    const int* dst = eidx + NE;
    const float* w1 = (const float*)d_in[2];  const float* b1 = (const float*)d_in[3];
    const float* w2 = (const float*)d_in[4];  const float* b2 = (const float*)d_in[5];
    const float* w3 = (const float*)d_in[6];  const float* b3 = (const float*)d_in[7];
    const float* w4 = (const float*)d_in[8];  const float* b4 = (const float*)d_in[9];
    const float* w5 = (const float*)d_in[10]; const float* b5 = (const float*)d_in[11];
    const float* s1_wl = (const float*)d_in[12]; const float* s1_wr = (const float*)d_in[13];
    const float* s1_b  = (const float*)d_in[14];
    const float* s2_wl = (const float*)d_in[15]; const float* s2_wr = (const float*)d_in[16];
    const float* s2_b  = (const float*)d_in[17];
    const float* s3_wl = (const float*)d_in[18]; const float* s3_wr = (const float*)d_in[19];
    const float* s3_b  = (const float*)d_in[20];

    float* ws = (float*)d_ws;
    unsigned short* c1 = (unsigned short*)(ws);
    unsigned short* c2 = (unsigned short*)(ws + 1048576);
    unsigned short* c3 = (unsigned short*)(ws);
    unsigned short* c4 = (unsigned short*)(ws + 1048576);
    float* P5  = ws;                       // 4*256*32*32 f32, c3 dead by then
    float* ORG = ws + 1179648;
    unsigned short* f2 = (unsigned short*)(ws + 1573888);
    unsigned short* f3 = (unsigned short*)(ws + 1583104);
    unsigned short* f4 = (unsigned short*)(ws + 1619968);
    unsigned short* f5 = (unsigned short*)(ws + 1767424);
    float* adj     = ws + 2062336;
    float* adjT    = ws + 2127872;
    float* s_soft  = ws + 2193408;
    float* T       = ws + 2226176;
    float* x1g     = ws + 2258944;
    float* lpart   = ws + 2259456;
    float* entp    = ws + 2259712;
    float* s_softT = ws + 2259968;   // 128*256

    float* fout = (float*)d_out;
    float* out_main  = fout;
    float* out_link  = fout + 256;
    float* out_ent   = fout + 257;
    float* out_nodes = fout + 258;
    float* out_eb    = fout + 514;

    mega1_kernel<<<2781, 256, 0, stream>>>(input, w1, b1, c1, w2, w3, w4, w5,
                                           f2, f3, f4, f5, src, dst, adj, adjT);
    conv_mfma<32,  64, 256, 64, 1><<<dim3(16, 32, 1), 256, 0, stream>>>(c1, f2, b2, c2);
    conv_mfma<64, 128, 128, 64, 1><<<dim3(8, 16, 2),  256, 0, stream>>>(c2, f3, b3, c3);
    conv_mfma<128, 256, 64, 32, 1><<<dim3(4, 8, 8),   256, 0, stream>>>(c3, f4, b4, c4);
    conv_mfma<256, 256, 32, 32, 4><<<dim3(2, 4, 32),  256, 0, stream>>>(c4, f5, b5, P5);
    finalize_pool<256, 16, 4><<<256, 256, 0, stream>>>(P5, b5, ORG);

    node_fused_kernel<<<256, 256, 0, stream>>>(adjT, ORG, s1_wl, s1_wr, s1_b,
                                               s2_wl, s2_wr, s2_b, s_soft, s_softT, x1g, entp);
    row_fused_kernel<<<256, 256, 0, stream>>>(adj, s_soft, s_softT, T, lpart);
    cluster_fused_kernel<<<128, 256, 0, stream>>>(s_softT, T, x1g, out_eb, out_nodes);
    final_kernel<<<1, 256, 0, stream>>>(lpart, entp, out_eb, out_nodes,
                                        s3_wl, s3_wr, s3_b, out_main, out_link, out_ent);
}

// Round 13
// 103.308 us; speedup vs baseline: 3.5509x; 1.0156x over previous
//
#include <hip/hip_runtime.h>
#include <math.h>

#define NN 256
#define NE 4096
#define NC 128

using short8  = __attribute__((ext_vector_type(8))) short;
using short4v = __attribute__((ext_vector_type(4))) short;
using f32x4   = __attribute__((ext_vector_type(4))) float;

static __device__ __forceinline__ unsigned short f2bf(float x) {
    unsigned u = __float_as_uint(x);
    unsigned r = (u + 0x7FFF + ((u >> 16) & 1)) >> 16;   // RNE
    return (unsigned short)r;
}

static __device__ __forceinline__ float block_sum_256(float v, float* red4) {
    #pragma unroll
    for (int o = 32; o > 0; o >>= 1) v += __shfl_xor(v, o);
    __syncthreads();
    if ((threadIdx.x & 63) == 0) red4[threadIdx.x >> 6] = v;
    __syncthreads();
    return (red4[0] + red4[1]) + (red4[2] + red4[3]);
}

// ============ mega dispatch 1: conv1(inline frags) + f2-f5 prep + adj/adjT rows ============
// blocks [0,2048): conv1 MFMA tiles; [2048,2525): wfrag f2-f5; [2525,2781): adj rows
__global__ __launch_bounds__(256) void mega1_kernel(
    const float* __restrict__ in, const float* __restrict__ w1, const float* __restrict__ bias1,
    unsigned short* __restrict__ c1out,
    const float* __restrict__ w2, const float* __restrict__ w3, const float* __restrict__ w4,
    const float* __restrict__ w5,
    unsigned short* __restrict__ f2, unsigned short* __restrict__ f3,
    unsigned short* __restrict__ f4, unsigned short* __restrict__ f5,
    const int* __restrict__ src, const int* __restrict__ dst,
    float* __restrict__ adj, float* __restrict__ adjT)
{
    const int bid = blockIdx.x;
    const int tid = threadIdx.x;
    if (bid >= 2525) {           // ---- adj/adjT row build (atomic-free to global, LDS ints) ----
        __shared__ int cntA[256], cntT[256];
        const int n = bid - 2525;
        cntA[tid] = 0; cntT[tid] = 0;
        __syncthreads();
        #pragma unroll
        for (int i = 0; i < 16; ++i) {
            int e = tid + i * 256;
            int s = src[e], d = dst[e];
            if (s == n) atomicAdd(&cntA[d], 1);
            if (d == n) atomicAdd(&cntT[s], 1);
        }
        __syncthreads();
        adj[n * NN + tid]  = (float)cntA[tid];
        adjT[n * NN + tid] = (float)cntT[tid];
        return;
    }
    if (bid >= 2048) {           // ---- wfrag prep for convs 2-5 ----
        int b = bid - 2048;
        const float* w; unsigned short* f; int CIN, NG, NCH, base;
        if (b < 9)        { w = w2; f = f2; CIN = 32;  NG = 4;  NCH = 1; base = 0;   }
        else if (b < 45)  { w = w3; f = f3; CIN = 64;  NG = 8;  NCH = 2; base = 9;   }
        else if (b < 189) { w = w4; f = f4; CIN = 128; NG = 16; NCH = 4; base = 45;  }
        else              { w = w5; f = f5; CIN = 256; NG = 16; NCH = 8; base = 189; }
        int idx = (b - base) * 256 + tid;
        int lane = idx & 63, rest = idx >> 6;
        int c = rest % NCH; rest /= NCH;
        int g = rest % NG;  int t = rest / NG;
        if (t >= 9) return;
        int oc = g * 16 + (lane & 15);
        int cin0 = c * 32 + (lane >> 4) * 8;
        short8 v;
        #pragma unroll
        for (int j = 0; j < 8; ++j) {
            v[j] = (short)f2bf(w[((size_t)oc * CIN + cin0 + j) * 9 + t]);
        }
        *(short8*)&f[(size_t)idx * 8] = v;
        return;
    }
    // ---- conv1: f32 NCHW 3x512x512 -> pooled bf16 ch-last [256][256][32] ----
    constexpr int Hc = 512;
    const int lane = tid & 63, wid = tid >> 6;
    const int col = lane & 15, kgl = lane >> 4;
    const int X0 = (bid & 31) * 16, Y0 = (bid >> 5) * 8;
    __shared__ __align__(16) unsigned short lds[10][18][4];
    if (tid < 180) {
        int hy = tid / 18, hx = tid - hy * 18;
        int gy = Y0 + hy - 1, gx = X0 + hx - 1;
        float v0 = 0.f, v1 = 0.f, v2 = 0.f;
        if (gy >= 0 && gy < Hc && gx >= 0 && gx < Hc) {
            v0 = in[0 * 262144 + gy * 512 + gx];
            v1 = in[1 * 262144 + gy * 512 + gx];
            v2 = in[2 * 262144 + gy * 512 + gx];
        }
        uint2 uu;
        uu.x = f2bf(v0) | ((unsigned)f2bf(v1) << 16);
        uu.y = f2bf(v2);
        *(uint2*)&lds[hy][hx][0] = uu;
    }
    // inline A-frags from w1 (slot0: k=tap*4+ch taps 0-7; slot1: k=ch tap 8)
    short8 af[2][2];
    #pragma unroll
    for (int slot = 0; slot < 2; ++slot) {
        #pragma unroll
        for (int g = 0; g < 2; ++g) {
            int oc = g * 16 + (lane & 15);
            short8 v;
            #pragma unroll
            for (int j = 0; j < 8; ++j) {
                int k = (lane >> 4) * 8 + j;
                float wv = 0.f;
                if (slot == 0) {
                    int tap = k >> 2, ch = k & 3;
                    if (ch < 3) wv = w1[oc * 27 + ch * 9 + tap];
                } else {
                    if (k < 3) wv = w1[oc * 27 + k * 9 + 8];
                }
                v[j] = (short)f2bf(wv);
            }
            af[slot][g] = v;
        }
    }
    __syncthreads();
    f32x4 acc[2][2];
    #pragma unroll
    for (int g = 0; g < 2; ++g) {
        #pragma unroll
        for (int r = 0; r < 2; ++r) acc[g][r] = {0.f, 0.f, 0.f, 0.f};
    }
    const int t0 = 2 * kgl, t1 = 2 * kgl + 1;
    const int dy0 = t0 / 3, dx0 = t0 % 3, dy1 = t1 / 3, dx1 = t1 % 3;
    #pragma unroll
    for (int r = 0; r < 2; ++r) {
        const int py = wid * 2 + r;
        short4v lo = *(const short4v*)&lds[py + dy0][col + dx0][0];
        short4v hi = *(const short4v*)&lds[py + dy1][col + dx1][0];
        short8 bf0 = __builtin_shufflevector(lo, hi, 0, 1, 2, 3, 4, 5, 6, 7);
        short4v z4 = {0, 0, 0, 0};
        short4v t8 = z4;
        if (kgl == 0) t8 = *(const short4v*)&lds[py + 2][col + 2][0];
        short8 bf1 = __builtin_shufflevector(t8, z4, 0, 1, 2, 3, 4, 5, 6, 7);
        #pragma unroll
        for (int g = 0; g < 2; ++g) {
            acc[g][r] = __builtin_amdgcn_mfma_f32_16x16x32_bf16(af[0][g], bf0, acc[g][r], 0, 0, 0);
            acc[g][r] = __builtin_amdgcn_mfma_f32_16x16x32_bf16(af[1][g], bf1, acc[g][r], 0, 0, 0);
        }
    }
    #pragma unroll
    for (int g = 0; g < 2; ++g) {
        const int oc = g * 16 + kgl * 4;
        const float4 bb = *(const float4*)&bias1[oc];
        const float bbv[4] = {bb.x, bb.y, bb.z, bb.w};
        float vv[4];
        #pragma unroll
        for (int q = 0; q < 4; ++q) {
            float v = fmaxf(acc[g][0][q], acc[g][1][q]);
            v = fmaxf(v, __shfl_xor(v, 1));
            vv[q] = fmaxf(v + bbv[q], 0.f);
        }
        if (!(col & 1)) {
            unsigned u0 = f2bf(vv[0]) | ((unsigned)f2bf(vv[1]) << 16);
            unsigned u1 = f2bf(vv[2]) | ((unsigned)f2bf(vv[3]) << 16);
            const int pry = Y0 / 2 + wid;
            const int prx = X0 / 2 + (col >> 1);
            uint2 uu; uu.x = u0; uu.y = u1;
            *(uint2*)&c1out[((size_t)(pry * 256 + prx)) * 32 + oc] = uu;
        }
    }
}

// ============ MFMA conv (convs 2-5), async dbuf staging, NTHR-parameterized ============
// NTHR=256 -> TR=8 (4 waves x 2 rows); NTHR=128 -> TR=4 (2 waves x 2 rows, 2+ blocks/CU)
// CSPLIT==1: fused bias+relu+pool2x2 -> bf16 ch-last [Hc/2][Hc/2][COUT]
// CSPLIT>1 : raw f32 partial out [cs][COUT][Hc][Hc]
template<int CIN, int COUT, int Hc, int OCB, int CSPLIT, int NTHR>
__global__ __launch_bounds__(NTHR) void conv_mfma(
    const unsigned short* __restrict__ in, const unsigned short* __restrict__ wfrag,
    const float* __restrict__ bias, void* __restrict__ outv)
{
    constexpr int TR = NTHR / 32;              // 2 rows per wave
    constexpr int NOG = OCB / 16;
    constexpr int NG  = COUT / 16;
    constexpr int NCHT = CIN / 32;
    constexpr int NCH = NCHT / CSPLIT;
    constexpr int RPW = 2;
    constexpr int ITEMS = (TR + 2) * 18 * 4;
    constexpr int NIT = (ITEMS + NTHR - 1) / NTHR;
    const int tid = threadIdx.x;
    const int lane = tid & 63, wid = tid >> 6;
    const int col = lane & 15, kgl = lane >> 4;
    const int X0 = blockIdx.x * 16, Y0 = blockIdx.y * TR;
    const int ob = blockIdx.z / CSPLIT, cs = blockIdx.z % CSPLIT;

    __shared__ __align__(16) unsigned short lds[2][ITEMS * 8];

    int ioff[NIT]; bool ival[NIT]; int loff[NIT];
    #pragma unroll
    for (int it = 0; it < NIT; ++it) {
        int i = tid + it * NTHR;
        int kg = i & 3, rem = i >> 2;
        int hx = rem % 18, hy = rem / 18;
        int gy = Y0 + hy - 1, gx = X0 + hx - 1;
        ival[it] = (i < ITEMS) && gy >= 0 && gy < Hc && gx >= 0 && gx < Hc;
        ioff[it] = (gy * Hc + gx) * CIN + kg * 8;
        loff[it] = ((hy * 4 + kg) * 18 + hx) * 8;
    }
    short8 sreg[NIT];
    auto sload = [&](int ca) {
        #pragma unroll
        for (int it = 0; it < NIT; ++it) {
            short8 v = {0, 0, 0, 0, 0, 0, 0, 0};
            if (ival[it]) v = *(const short8*)&in[ioff[it] + ca * 32];
            sreg[it] = v;
        }
    };
    auto swrite = [&](int buf) {
        #pragma unroll
        for (int it = 0; it < NIT; ++it) {
            if (tid + it * NTHR < ITEMS) *(short8*)&lds[buf][loff[it]] = sreg[it];
        }
    };

    f32x4 acc[NOG][RPW];
    #pragma unroll
    for (int g = 0; g < NOG; ++g) {
        #pragma unroll
        for (int r = 0; r < RPW; ++r) acc[g][r] = {0.f, 0.f, 0.f, 0.f};
    }

    sload(cs * NCH);
    swrite(0);
    __syncthreads();
    for (int cc = 0; cc < NCH; ++cc) {
        const int ca = cs * NCH + cc;
        if (cc + 1 < NCH) sload(ca + 1);          // issue next chunk's loads early
        const unsigned short* L = &lds[cc & 1][0];
        #pragma unroll
        for (int t = 0; t < 9; ++t) {
            const int ky = t / 3, kx = t % 3;
            short8 af[NOG];
            #pragma unroll
            for (int g = 0; g < NOG; ++g) {
                af[g] = *(const short8*)&wfrag[((((size_t)t * NG + ob * NOG + g) * NCHT + ca) * 64 + lane) * 8];
            }
            #pragma unroll
            for (int r = 0; r < RPW; ++r) {
                const int py = wid * RPW + r;
                short8 bf = *(const short8*)&L[(((py + ky) * 4 + kgl) * 18 + col + kx) * 8];
                #pragma unroll
                for (int g = 0; g < NOG; ++g) {
                    acc[g][r] = __builtin_amdgcn_mfma_f32_16x16x32_bf16(af[g], bf, acc[g][r], 0, 0, 0);
                }
            }
        }
        if (cc + 1 < NCH) { swrite((cc + 1) & 1); __syncthreads(); }
    }

    if constexpr (CSPLIT == 1) {
        constexpr int Wp = Hc / 2;
        unsigned short* outp = (unsigned short*)outv;
        #pragma unroll
        for (int g = 0; g < NOG; ++g) {
            const int oc = (ob * NOG + g) * 16 + kgl * 4;
            const float4 bb = *(const float4*)&bias[oc];
            const float bbv[4] = {bb.x, bb.y, bb.z, bb.w};
            float vv[4];
            #pragma unroll
            for (int q = 0; q < 4; ++q) {
                float v = fmaxf(acc[g][0][q], acc[g][1][q]);
                v = fmaxf(v, __shfl_xor(v, 1));
                vv[q] = fmaxf(v + bbv[q], 0.f);
            }
            if (!(col & 1)) {
                unsigned u0 = f2bf(vv[0]) | ((unsigned)f2bf(vv[1]) << 16);
                unsigned u1 = f2bf(vv[2]) | ((unsigned)f2bf(vv[3]) << 16);
                const int pry = Y0 / 2 + wid;
                const int prx = X0 / 2 + (col >> 1);
                uint2 uu; uu.x = u0; uu.y = u1;
                *(uint2*)&outp[((size_t)(pry * Wp + prx)) * COUT + oc] = uu;
            }
        }
    } else {
        float* po = (float*)outv;
        #pragma unroll
        for (int g = 0; g < NOG; ++g) {
            #pragma unroll
            for (int r = 0; r < RPW; ++r) {
                const int gy = Y0 + wid * RPW + r;
                #pragma unroll
                for (int q = 0; q < 4; ++q) {
                    const int oc = (ob * NOG + g) * 16 + kgl * 4 + q;
                    po[((size_t)(cs * COUT + oc) * Hc + gy) * Hc + X0 + col] = acc[g][r][q];
                }
            }
        }
    }
}

// sum CS pre-pool f32 partials, add bias, relu, 2x2 maxpool -> f32 channel-major out
template<int COUT, int HP, int CS>
__global__ void finalize_pool(const float* __restrict__ partial, const float* __restrict__ bias,
                              float* __restrict__ out)
{
    int idx = blockIdx.x * 256 + threadIdx.x;
    if (idx >= COUT * HP * HP) return;
    constexpr int H = HP * 2;
    int x = idx & (HP - 1); int rest = idx / HP;
    int y = rest & (HP - 1); int oc = rest / HP;
    float v00 = 0.f, v01 = 0.f, v10 = 0.f, v11 = 0.f;
    #pragma unroll
    for (int cs = 0; cs < CS; ++cs) {
        const float* p = partial + ((size_t)(cs * COUT + oc) * H + 2 * y) * H + 2 * x;
        v00 += p[0]; v01 += p[1]; v10 += p[H]; v11 += p[H + 1];
    }
    float m = fmaxf(fmaxf(v00, v01), fmaxf(v10, v11)) + bias[oc];
    out[idx] = fmaxf(m, 0.f);
}

// ============ fused graph tail ============

__global__ __launch_bounds__(256) void node_fused_kernel(
    const float* __restrict__ adjT, const float* __restrict__ org,
    const float* __restrict__ s1wl, const float* __restrict__ s1wr, const float* __restrict__ s1b,
    const float* __restrict__ s2wl, const float* __restrict__ s2wr, const float* __restrict__ s2b,
    float* __restrict__ s_soft, float* __restrict__ s_softT,
    float* __restrict__ x1g, float* __restrict__ entp)
{
    int n = blockIdx.x, t = threadIdx.x;
    __shared__ float rowT[256], orgn[256], aggn[256], red[256], sm[128], red4[4];
    float rT = adjT[n * 256 + t];
    rowT[t] = rT; orgn[t] = org[n * 256 + t];
    __syncthreads();
    float cnt = block_sum_256(rT, red4);
    float a0 = 0.f, a1 = 0.f, a2 = 0.f, a3 = 0.f;
    #pragma unroll 8
    for (int s = 0; s < 256; s += 4) {
        a0 = fmaf(rowT[s + 0], org[(s + 0) * 256 + t], a0);
        a1 = fmaf(rowT[s + 1], org[(s + 1) * 256 + t], a1);
        a2 = fmaf(rowT[s + 2], org[(s + 2) * 256 + t], a2);
        a3 = fmaf(rowT[s + 3], org[(s + 3) * 256 + t], a3);
    }
    float acc = (a0 + a1) + (a2 + a3);
    float aggv = (cnt > 0.f) ? acc / cnt : 0.f;
    aggn[t] = aggv;
    float orgv = orgn[t];
    float x10 = block_sum_256(aggv * s1wl[2 * t] + orgv * s1wr[2 * t], red4) + s1b[0];
    float x11 = block_sum_256(aggv * s1wl[2 * t + 1] + orgv * s1wr[2 * t + 1], red4) + s1b[1];
    if (t == 0) { x1g[n * 2 + 0] = x10; x1g[n * 2 + 1] = x11; }
    int p = t & 127, h = t >> 7;
    float b0 = 0.f, b1 = 0.f, b2 = 0.f, b3 = 0.f;
    #pragma unroll 8
    for (int k = h * 128; k < h * 128 + 128; k += 2) {
        b0 = fmaf(aggn[k],     s2wl[k * NC + p],       b0);
        b1 = fmaf(orgn[k],     s2wr[k * NC + p],       b1);
        b2 = fmaf(aggn[k + 1], s2wl[(k + 1) * NC + p], b2);
        b3 = fmaf(orgn[k + 1], s2wr[(k + 1) * NC + p], b3);
    }
    red[t] = (b0 + b1) + (b2 + b3);
    __syncthreads();
    if (t < 128) sm[p] = red[t] + red[t + 128] + s2b[p];
    __syncthreads();
    if (t < 128) red[t] = sm[t];
    __syncthreads();
    for (int s = 64; s > 0; s >>= 1) { if (t < s) red[t] = fmaxf(red[t], red[t + s]); __syncthreads(); }
    float mx = red[0];
    __syncthreads();
    float e = 0.f;
    if (t < 128) { e = expf(sm[t] - mx); red[t] = e; } else { red[t] = 0.f; }
    __syncthreads();
    for (int s = 64; s > 0; s >>= 1) { if (t < s) red[t] += red[t + s]; __syncthreads(); }
    float denom = red[0];
    float q = e / denom;
    if (t < 128) {
        s_soft[n * NC + t] = q;
        s_softT[t * 256 + n] = q;
    }
    float ev = (t < 128) ? -q * logf(q + 1e-15f) : 0.f;
    float esum = block_sum_256(ev, red4);
    if (t == 0) entp[n] = esum;
}

__global__ __launch_bounds__(256) void row_fused_kernel(
    const float* __restrict__ adj, const float* __restrict__ s_soft,
    const float* __restrict__ s_softT, float* __restrict__ T, float* __restrict__ lpart)
{
    int i = blockIdx.x, j = threadIdx.x;
    __shared__ float si[NC], adjrow[256], tbuf[256], red4[4];
    adjrow[j] = adj[i * 256 + j];
    if (j < NC) si[j] = s_soft[i * NC + j];
    __syncthreads();
    float d0 = 0.f, d1 = 0.f, d2 = 0.f, d3 = 0.f;
    #pragma unroll 8
    for (int k = 0; k < NC; k += 4) {
        d0 = fmaf(si[k + 0], s_softT[(k + 0) * 256 + j], d0);
        d1 = fmaf(si[k + 1], s_softT[(k + 1) * 256 + j], d1);
        d2 = fmaf(si[k + 2], s_softT[(k + 2) * 256 + j], d2);
        d3 = fmaf(si[k + 3], s_softT[(k + 3) * 256 + j], d3);
    }
    float dot = (d0 + d1) + (d2 + d3);
    float dd = adjrow[j] - dot;
    float lsum = block_sum_256(dd * dd, red4);
    if (j == 0) lpart[i] = lsum;
    int p = j & 127, h = j >> 7;
    float a0 = 0.f, a1 = 0.f;
    #pragma unroll 8
    for (int k = h * 128; k < h * 128 + 128; k += 2) {
        a0 = fmaf(adjrow[k],     s_soft[k * NC + p],       a0);
        a1 = fmaf(adjrow[k + 1], s_soft[(k + 1) * NC + p], a1);
    }
    tbuf[j] = a0 + a1;
    __syncthreads();
    if (j < 128) T[i * NC + j] = tbuf[j] + tbuf[j + 128];
}

__global__ __launch_bounds__(256) void cluster_fused_kernel(
    const float* __restrict__ s_softT, const float* __restrict__ T, const float* __restrict__ x1g,
    float* __restrict__ eb_out, float* __restrict__ nodes_out)
{
    int c = blockIdx.x, t = threadIdx.x;
    __shared__ float colc[256], red[256], ap[NC], red4[4];
    colc[t] = s_softT[c * 256 + t];
    __syncthreads();
    int p = t & 127, h = t >> 7;
    float a0 = 0.f, a1 = 0.f;
    #pragma unroll 8
    for (int n = h * 128; n < h * 128 + 128; n += 2) {
        a0 = fmaf(colc[n],     T[n * NC + p],       a0);
        a1 = fmaf(colc[n + 1], T[(n + 1) * NC + p], a1);
    }
    red[t] = a0 + a1;
    __syncthreads();
    if (t < 128) ap[t] = red[t] + red[t + 128];
    __syncthreads();
    if (t < 128) red[t] = ap[t];
    __syncthreads();
    for (int s = 64; s > 0; s >>= 1) { if (t < s) red[t] = fmaxf(red[t], red[t + s]); __syncthreads(); }
    float mx = red[0];
    if (t < 128) eb_out[c * NC + t] = (ap[t] == mx) ? 1.f : 0.f;
    float n0 = tanhf(block_sum_256(colc[t] * x1g[t * 2 + 0], red4));
    float n1 = tanhf(block_sum_256(colc[t] * x1g[t * 2 + 1], red4));
    if (t == 0) { nodes_out[c * 2 + 0] = n0; nodes_out[c * 2 + 1] = n1; }
}

__global__ __launch_bounds__(256) void final_kernel(
    const float* __restrict__ lpart, const float* __restrict__ entp,
    const float* __restrict__ eb, const float* __restrict__ nodes,
    const float* __restrict__ wl, const float* __restrict__ wr, const float* __restrict__ b,
    float* __restrict__ out_main, float* __restrict__ out_link, float* __restrict__ out_ent)
{
    int t = threadIdx.x;
    __shared__ float red4[4];
    float ls = block_sum_256(lpart[t], red4);
    if (t == 0) out_link[0] = sqrtf(ls) / (float)(NN * NN);
    float es = block_sum_256(entp[t], red4);
    if (t == 0) out_ent[0] = es / (float)NN;
    if (t < NC) {
        int j = t;
        float i0 = 0.f, i1 = 0.f, a00 = 0.f, a01 = 0.f, a10 = 0.f, a11 = 0.f;
        #pragma unroll 8
        for (int i2 = 0; i2 < NC; i2 += 2) {
            float e0 = eb[i2 * NC + j];
            float e1 = eb[(i2 + 1) * NC + j];
            i0 += e0; i1 += e1;
            a00 = fmaf(e0, nodes[i2 * 2 + 0], a00);
            a01 = fmaf(e0, nodes[i2 * 2 + 1], a01);
            a10 = fmaf(e1, nodes[(i2 + 1) * 2 + 0], a10);
            a11 = fmaf(e1, nodes[(i2 + 1) * 2 + 1], a11);
        }
        float indeg = i0 + i1;
        float a0 = a00 + a10, a1 = a01 + a11;
        float inv = (indeg > 0.f) ? 1.f / fmaxf(indeg, 1.f) : 0.f;
        float g0 = a0 * inv, g1 = a1 * inv;
        float n0 = nodes[j * 2 + 0], n1 = nodes[j * 2 + 1];
        out_main[j * 2 + 0] = g0 * wl[0] + g1 * wl[2] + b[0] + n0 * wr[0] + n1 * wr[2];
        out_main[j * 2 + 1] = g0 * wl[1] + g1 * wl[3] + b[1] + n0 * wr[1] + n1 * wr[3];
    }
}

extern "C" void kernel_launch(void* const* d_in, const int* in_sizes, int n_in,
                              void* d_out, int out_size, void* d_ws, size_t ws_size,
                              hipStream_t stream)
{
    const float* input = (const float*)d_in[0];
    const int* eidx = (const int*)d_in[1];
    const int* src = eidx;
    const int* dst = eidx + NE;
    const float* w1 = (const float*)d_in[2];  const float* b1 = (const float*)d_in[3];
    const float* w2 = (const float*)d_in[4];  const float* b2 = (const float*)d_in[5];
    const float* w3 = (const float*)d_in[6];  const float* b3 = (const float*)d_in[7];
    const float* w4 = (const float*)d_in[8];  const float* b4 = (const float*)d_in[9];
    const float* w5 = (const float*)d_in[10]; const float* b5 = (const float*)d_in[11];
    const float* s1_wl = (const float*)d_in[12]; const float* s1_wr = (const float*)d_in[13];
    const float* s1_b  = (const float*)d_in[14];
    const float* s2_wl = (const float*)d_in[15]; const float* s2_wr = (const float*)d_in[16];
    const float* s2_b  = (const float*)d_in[17];
    const float* s3_wl = (const float*)d_in[18]; const float* s3_wr = (const float*)d_in[19];
    const float* s3_b  = (const float*)d_in[20];

    float* ws = (float*)d_ws;
    unsigned short* c1 = (unsigned short*)(ws);
    unsigned short* c2 = (unsigned short*)(ws + 1048576);
    unsigned short* c3 = (unsigned short*)(ws);
    unsigned short* c4 = (unsigned short*)(ws + 1048576);
    float* P5  = ws;                       // 4*256*32*32 f32, c3 dead by then
    float* ORG = ws + 1179648;
    unsigned short* f2 = (unsigned short*)(ws + 1573888);
    unsigned short* f3 = (unsigned short*)(ws + 1583104);
    unsigned short* f4 = (unsigned short*)(ws + 1619968);
    unsigned short* f5 = (unsigned short*)(ws + 1767424);
    float* adj     = ws + 2062336;
    float* adjT    = ws + 2127872;
    float* s_soft  = ws + 2193408;
    float* T       = ws + 2226176;
    float* x1g     = ws + 2258944;
    float* lpart   = ws + 2259456;
    float* entp    = ws + 2259712;
    float* s_softT = ws + 2259968;   // 128*256

    float* fout = (float*)d_out;
    float* out_main  = fout;
    float* out_link  = fout + 256;
    float* out_ent   = fout + 257;
    float* out_nodes = fout + 258;
    float* out_eb    = fout + 514;

    mega1_kernel<<<2781, 256, 0, stream>>>(input, w1, b1, c1, w2, w3, w4, w5,
                                           f2, f3, f4, f5, src, dst, adj, adjT);
    conv_mfma<32,  64, 256, 64, 1, 128><<<dim3(16, 64, 1), 128, 0, stream>>>(c1, f2, b2, c2);
    conv_mfma<64, 128, 128, 64, 1, 128><<<dim3(8, 32, 2),  128, 0, stream>>>(c2, f3, b3, c3);
    conv_mfma<128, 256, 64, 32, 1, 128><<<dim3(4, 16, 8),  128, 0, stream>>>(c3, f4, b4, c4);
    conv_mfma<256, 256, 32, 32, 4, 128><<<dim3(2, 8, 32),  128, 0, stream>>>(c4, f5, b5, P5);
    finalize_pool<256, 16, 4><<<256, 256, 0, stream>>>(P5, b5, ORG);

    node_fused_kernel<<<256, 256, 0, stream>>>(adjT, ORG, s1_wl, s1_wr, s1_b,
                                               s2_wl, s2_wr, s2_b, s_soft, s_softT, x1g, entp);
    row_fused_kernel<<<256, 256, 0, stream>>>(adj, s_soft, s_softT, T, lpart);
    cluster_fused_kernel<<<128, 256, 0, stream>>>(s_softT, T, x1g, out_eb, out_nodes);
    final_kernel<<<1, 256, 0, stream>>>(lpart, entp, out_eb, out_nodes,
                                        s3_wl, s3_wr, s3_b, out_main, out_link, out_ent);
}

// Round 14
// 100.179 us; speedup vs baseline: 3.6618x; 1.0312x over previous
//
#include <hip/hip_runtime.h>
#include <math.h>

#define NN 256
#define NE 4096
#define NC 128

using short8  = __attribute__((ext_vector_type(8))) short;
using short4v = __attribute__((ext_vector_type(4))) short;
using f32x4   = __attribute__((ext_vector_type(4))) float;

static __device__ __forceinline__ unsigned short f2bf(float x) {
    unsigned u = __float_as_uint(x);
    unsigned r = (u + 0x7FFF + ((u >> 16) & 1)) >> 16;   // RNE
    return (unsigned short)r;
}

static __device__ __forceinline__ float block_sum_256(float v, float* red4) {
    #pragma unroll
    for (int o = 32; o > 0; o >>= 1) v += __shfl_xor(v, o);
    __syncthreads();
    if ((threadIdx.x & 63) == 0) red4[threadIdx.x >> 6] = v;
    __syncthreads();
    return (red4[0] + red4[1]) + (red4[2] + red4[3]);
}

// ============ mega dispatch 1: conv1(LDS-coop frags) + f2-f5 prep + adj/adjT rows ============
// blocks [0,2048): conv1 MFMA tiles; [2048,2525): wfrag f2-f5; [2525,2781): adj rows
__global__ __launch_bounds__(256) void mega1_kernel(
    const float* __restrict__ in, const float* __restrict__ w1, const float* __restrict__ bias1,
    unsigned short* __restrict__ c1out,
    const float* __restrict__ w2, const float* __restrict__ w3, const float* __restrict__ w4,
    const float* __restrict__ w5,
    unsigned short* __restrict__ f2, unsigned short* __restrict__ f3,
    unsigned short* __restrict__ f4, unsigned short* __restrict__ f5,
    const int* __restrict__ src, const int* __restrict__ dst,
    float* __restrict__ adj, float* __restrict__ adjT)
{
    const int bid = blockIdx.x;
    const int tid = threadIdx.x;
    if (bid >= 2525) {           // ---- adj/adjT row build (atomic-free to global, LDS ints) ----
        __shared__ int cntA[256], cntT[256];
        const int n = bid - 2525;
        cntA[tid] = 0; cntT[tid] = 0;
        __syncthreads();
        #pragma unroll
        for (int i = 0; i < 16; ++i) {
            int e = tid + i * 256;
            int s = src[e], d = dst[e];
            if (s == n) atomicAdd(&cntA[d], 1);
            if (d == n) atomicAdd(&cntT[s], 1);
        }
        __syncthreads();
        adj[n * NN + tid]  = (float)cntA[tid];
        adjT[n * NN + tid] = (float)cntT[tid];
        return;
    }
    if (bid >= 2048) {           // ---- wfrag prep for convs 2-5 ----
        int b = bid - 2048;
        const float* w; unsigned short* f; int CIN, NG, NCH, base;
        if (b < 9)        { w = w2; f = f2; CIN = 32;  NG = 4;  NCH = 1; base = 0;   }
        else if (b < 45)  { w = w3; f = f3; CIN = 64;  NG = 8;  NCH = 2; base = 9;   }
        else if (b < 189) { w = w4; f = f4; CIN = 128; NG = 16; NCH = 4; base = 45;  }
        else              { w = w5; f = f5; CIN = 256; NG = 16; NCH = 8; base = 189; }
        int idx = (b - base) * 256 + tid;
        int lane = idx & 63, rest = idx >> 6;
        int c = rest % NCH; rest /= NCH;
        int g = rest % NG;  int t = rest / NG;
        if (t >= 9) return;
        int oc = g * 16 + (lane & 15);
        int cin0 = c * 32 + (lane >> 4) * 8;
        short8 v;
        #pragma unroll
        for (int j = 0; j < 8; ++j) {
            v[j] = (short)f2bf(w[((size_t)oc * CIN + cin0 + j) * 9 + t]);
        }
        *(short8*)&f[(size_t)idx * 8] = v;
        return;
    }
    // ---- conv1: f32 NCHW 3x512x512 -> pooled bf16 ch-last [256][256][32] ----
    constexpr int Hc = 512;
    const int lane = tid & 63, wid = tid >> 6;
    const int col = lane & 15, kgl = lane >> 4;
    const int X0 = (bid & 31) * 16, Y0 = (bid >> 5) * 8;
    __shared__ __align__(16) unsigned short lds[10][18][4];
    __shared__ __align__(16) unsigned short wl1[2048];   // [slot*2+g][lane][8]
    if (tid < 180) {
        int hy = tid / 18, hx = tid - hy * 18;
        int gy = Y0 + hy - 1, gx = X0 + hx - 1;
        float v0 = 0.f, v1 = 0.f, v2 = 0.f;
        if (gy >= 0 && gy < Hc && gx >= 0 && gx < Hc) {
            v0 = in[0 * 262144 + gy * 512 + gx];
            v1 = in[1 * 262144 + gy * 512 + gx];
            v2 = in[2 * 262144 + gy * 512 + gx];
        }
        uint2 uu;
        uu.x = f2bf(v0) | ((unsigned)f2bf(v1) << 16);
        uu.y = f2bf(v2);
        *(uint2*)&lds[hy][hx][0] = uu;
    }
    // cooperative frag build: each thread computes ONE 8-elem frag slice (8 scattered loads)
    {
        int lane_ = tid & 63, rest = tid >> 6;
        int g = rest & 1, slot = rest >> 1;
        int oc = g * 16 + (lane_ & 15);
        short8 v;
        #pragma unroll
        for (int j = 0; j < 8; ++j) {
            int k = (lane_ >> 4) * 8 + j;
            float wv = 0.f;
            if (slot == 0) {
                int tap = k >> 2, ch = k & 3;
                if (ch < 3) wv = w1[oc * 27 + ch * 9 + tap];
            } else {
                if (k < 3) wv = w1[oc * 27 + k * 9 + 8];
            }
            v[j] = (short)f2bf(wv);
        }
        *(short8*)&wl1[(size_t)tid * 8] = v;
    }
    __syncthreads();
    short8 af[2][2];
    #pragma unroll
    for (int slot = 0; slot < 2; ++slot) {
        #pragma unroll
        for (int g = 0; g < 2; ++g) {
            af[slot][g] = *(const short8*)&wl1[((size_t)((slot * 2 + g) * 64 + lane)) * 8];
        }
    }
    f32x4 acc[2][2];
    #pragma unroll
    for (int g = 0; g < 2; ++g) {
        #pragma unroll
        for (int r = 0; r < 2; ++r) acc[g][r] = {0.f, 0.f, 0.f, 0.f};
    }
    const int t0 = 2 * kgl, t1 = 2 * kgl + 1;
    const int dy0 = t0 / 3, dx0 = t0 % 3, dy1 = t1 / 3, dx1 = t1 % 3;
    #pragma unroll
    for (int r = 0; r < 2; ++r) {
        const int py = wid * 2 + r;
        short4v lo = *(const short4v*)&lds[py + dy0][col + dx0][0];
        short4v hi = *(const short4v*)&lds[py + dy1][col + dx1][0];
        short8 bf0 = __builtin_shufflevector(lo, hi, 0, 1, 2, 3, 4, 5, 6, 7);
        short4v z4 = {0, 0, 0, 0};
        short4v t8 = z4;
        if (kgl == 0) t8 = *(const short4v*)&lds[py + 2][col + 2][0];
        short8 bf1 = __builtin_shufflevector(t8, z4, 0, 1, 2, 3, 4, 5, 6, 7);
        #pragma unroll
        for (int g = 0; g < 2; ++g) {
            acc[g][r] = __builtin_amdgcn_mfma_f32_16x16x32_bf16(af[0][g], bf0, acc[g][r], 0, 0, 0);
            acc[g][r] = __builtin_amdgcn_mfma_f32_16x16x32_bf16(af[1][g], bf1, acc[g][r], 0, 0, 0);
        }
    }
    #pragma unroll
    for (int g = 0; g < 2; ++g) {
        const int oc = g * 16 + kgl * 4;
        const float4 bb = *(const float4*)&bias1[oc];
        const float bbv[4] = {bb.x, bb.y, bb.z, bb.w};
        float vv[4];
        #pragma unroll
        for (int q = 0; q < 4; ++q) {
            float v = fmaxf(acc[g][0][q], acc[g][1][q]);
            v = fmaxf(v, __shfl_xor(v, 1));
            vv[q] = fmaxf(v + bbv[q], 0.f);
        }
        if (!(col & 1)) {
            unsigned u0 = f2bf(vv[0]) | ((unsigned)f2bf(vv[1]) << 16);
            unsigned u1 = f2bf(vv[2]) | ((unsigned)f2bf(vv[3]) << 16);
            const int pry = Y0 / 2 + wid;
            const int prx = X0 / 2 + (col >> 1);
            uint2 uu; uu.x = u0; uu.y = u1;
            *(uint2*)&c1out[((size_t)(pry * 256 + prx)) * 32 + oc] = uu;
        }
    }
}

// ============ MFMA conv (convs 2-5), async dbuf staging, NTHR-parameterized ============
// NTHR=128 -> TR=4 (2 waves x 2 rows, 2+ blocks/CU)
// CSPLIT==1: fused bias+relu+pool2x2 -> bf16 ch-last [Hc/2][Hc/2][COUT]
// CSPLIT>1 : raw f32 partial out [cs][COUT][Hc][Hc]
template<int CIN, int COUT, int Hc, int OCB, int CSPLIT, int NTHR>
__global__ __launch_bounds__(NTHR) void conv_mfma(
    const unsigned short* __restrict__ in, const unsigned short* __restrict__ wfrag,
    const float* __restrict__ bias, void* __restrict__ outv)
{
    constexpr int TR = NTHR / 32;              // 2 rows per wave
    constexpr int NOG = OCB / 16;
    constexpr int NG  = COUT / 16;
    constexpr int NCHT = CIN / 32;
    constexpr int NCH = NCHT / CSPLIT;
    constexpr int RPW = 2;
    constexpr int ITEMS = (TR + 2) * 18 * 4;
    constexpr int NIT = (ITEMS + NTHR - 1) / NTHR;
    const int tid = threadIdx.x;
    const int lane = tid & 63, wid = tid >> 6;
    const int col = lane & 15, kgl = lane >> 4;
    const int X0 = blockIdx.x * 16, Y0 = blockIdx.y * TR;
    const int ob = blockIdx.z / CSPLIT, cs = blockIdx.z % CSPLIT;

    __shared__ __align__(16) unsigned short lds[2][ITEMS * 8];

    int ioff[NIT]; bool ival[NIT]; int loff[NIT];
    #pragma unroll
    for (int it = 0; it < NIT; ++it) {
        int i = tid + it * NTHR;
        int kg = i & 3, rem = i >> 2;
        int hx = rem % 18, hy = rem / 18;
        int gy = Y0 + hy - 1, gx = X0 + hx - 1;
        ival[it] = (i < ITEMS) && gy >= 0 && gy < Hc && gx >= 0 && gx < Hc;
        ioff[it] = (gy * Hc + gx) * CIN + kg * 8;
        loff[it] = ((hy * 4 + kg) * 18 + hx) * 8;
    }
    short8 sreg[NIT];
    auto sload = [&](int ca) {
        #pragma unroll
        for (int it = 0; it < NIT; ++it) {
            short8 v = {0, 0, 0, 0, 0, 0, 0, 0};
            if (ival[it]) v = *(const short8*)&in[ioff[it] + ca * 32];
            sreg[it] = v;
        }
    };
    auto swrite = [&](int buf) {
        #pragma unroll
        for (int it = 0; it < NIT; ++it) {
            if (tid + it * NTHR < ITEMS) *(short8*)&lds[buf][loff[it]] = sreg[it];
        }
    };

    f32x4 acc[NOG][RPW];
    #pragma unroll
    for (int g = 0; g < NOG; ++g) {
        #pragma unroll
        for (int r = 0; r < RPW; ++r) acc[g][r] = {0.f, 0.f, 0.f, 0.f};
    }

    sload(cs * NCH);
    swrite(0);
    __syncthreads();
    for (int cc = 0; cc < NCH; ++cc) {
        const int ca = cs * NCH + cc;
        if (cc + 1 < NCH) sload(ca + 1);          // issue next chunk's loads early
        const unsigned short* L = &lds[cc & 1][0];
        #pragma unroll
        for (int t = 0; t < 9; ++t) {
            const int ky = t / 3, kx = t % 3;
            short8 af[NOG];
            #pragma unroll
            for (int g = 0; g < NOG; ++g) {
                af[g] = *(const short8*)&wfrag[((((size_t)t * NG + ob * NOG + g) * NCHT + ca) * 64 + lane) * 8];
            }
            #pragma unroll
            for (int r = 0; r < RPW; ++r) {
                const int py = wid * RPW + r;
                short8 bf = *(const short8*)&L[(((py + ky) * 4 + kgl) * 18 + col + kx) * 8];
                #pragma unroll
                for (int g = 0; g < NOG; ++g) {
                    acc[g][r] = __builtin_amdgcn_mfma_f32_16x16x32_bf16(af[g], bf, acc[g][r], 0, 0, 0);
                }
            }
        }
        if (cc + 1 < NCH) { swrite((cc + 1) & 1); __syncthreads(); }
    }

    if constexpr (CSPLIT == 1) {
        constexpr int Wp = Hc / 2;
        unsigned short* outp = (unsigned short*)outv;
        #pragma unroll
        for (int g = 0; g < NOG; ++g) {
            const int oc = (ob * NOG + g) * 16 + kgl * 4;
            const float4 bb = *(const float4*)&bias[oc];
            const float bbv[4] = {bb.x, bb.y, bb.z, bb.w};
            float vv[4];
            #pragma unroll
            for (int q = 0; q < 4; ++q) {
                float v = fmaxf(acc[g][0][q], acc[g][1][q]);
                v = fmaxf(v, __shfl_xor(v, 1));
                vv[q] = fmaxf(v + bbv[q], 0.f);
            }
            if (!(col & 1)) {
                unsigned u0 = f2bf(vv[0]) | ((unsigned)f2bf(vv[1]) << 16);
                unsigned u1 = f2bf(vv[2]) | ((unsigned)f2bf(vv[3]) << 16);
                const int pry = Y0 / 2 + wid;
                const int prx = X0 / 2 + (col >> 1);
                uint2 uu; uu.x = u0; uu.y = u1;
                *(uint2*)&outp[((size_t)(pry * Wp + prx)) * COUT + oc] = uu;
            }
        }
    } else {
        float* po = (float*)outv;
        #pragma unroll
        for (int g = 0; g < NOG; ++g) {
            #pragma unroll
            for (int r = 0; r < RPW; ++r) {
                const int gy = Y0 + wid * RPW + r;
                #pragma unroll
                for (int q = 0; q < 4; ++q) {
                    const int oc = (ob * NOG + g) * 16 + kgl * 4 + q;
                    po[((size_t)(cs * COUT + oc) * Hc + gy) * Hc + X0 + col] = acc[g][r][q];
                }
            }
        }
    }
}

// sum CS pre-pool f32 partials, add bias, relu, 2x2 maxpool -> f32 channel-major out
template<int COUT, int HP, int CS>
__global__ void finalize_pool(const float* __restrict__ partial, const float* __restrict__ bias,
                              float* __restrict__ out)
{
    int idx = blockIdx.x * 256 + threadIdx.x;
    if (idx >= COUT * HP * HP) return;
    constexpr int H = HP * 2;
    int x = idx & (HP - 1); int rest = idx / HP;
    int y = rest & (HP - 1); int oc = rest / HP;
    float v00 = 0.f, v01 = 0.f, v10 = 0.f, v11 = 0.f;
    #pragma unroll
    for (int cs = 0; cs < CS; ++cs) {
        const float* p = partial + ((size_t)(cs * COUT + oc) * H + 2 * y) * H + 2 * x;
        v00 += p[0]; v01 += p[1]; v10 += p[H]; v11 += p[H + 1];
    }
    float m = fmaxf(fmaxf(v00, v01), fmaxf(v10, v11)) + bias[oc];
    out[idx] = fmaxf(m, 0.f);
}

// ============ fused graph tail ============

__global__ __launch_bounds__(256) void node_fused_kernel(
    const float* __restrict__ adjT, const float* __restrict__ org,
    const float* __restrict__ s1wl, const float* __restrict__ s1wr, const float* __restrict__ s1b,
    const float* __restrict__ s2wl, const float* __restrict__ s2wr, const float* __restrict__ s2b,
    float* __restrict__ s_soft, float* __restrict__ s_softT,
    float* __restrict__ x1g, float* __restrict__ entp)
{
    int n = blockIdx.x, t = threadIdx.x;
    __shared__ float rowT[256], orgn[256], aggn[256], red[256], sm[128], red4[4];
    float rT = adjT[n * 256 + t];
    rowT[t] = rT; orgn[t] = org[n * 256 + t];
    __syncthreads();
    float cnt = block_sum_256(rT, red4);
    float a0 = 0.f, a1 = 0.f, a2 = 0.f, a3 = 0.f;
    #pragma unroll 8
    for (int s = 0; s < 256; s += 4) {
        a0 = fmaf(rowT[s + 0], org[(s + 0) * 256 + t], a0);
        a1 = fmaf(rowT[s + 1], org[(s + 1) * 256 + t], a1);
        a2 = fmaf(rowT[s + 2], org[(s + 2) * 256 + t], a2);
        a3 = fmaf(rowT[s + 3], org[(s + 3) * 256 + t], a3);
    }
    float acc = (a0 + a1) + (a2 + a3);
    float aggv = (cnt > 0.f) ? acc / cnt : 0.f;
    aggn[t] = aggv;
    float orgv = orgn[t];
    float x10 = block_sum_256(aggv * s1wl[2 * t] + orgv * s1wr[2 * t], red4) + s1b[0];
    float x11 = block_sum_256(aggv * s1wl[2 * t + 1] + orgv * s1wr[2 * t + 1], red4) + s1b[1];
    if (t == 0) { x1g[n * 2 + 0] = x10; x1g[n * 2 + 1] = x11; }
    int p = t & 127, h = t >> 7;
    float b0 = 0.f, b1 = 0.f, b2 = 0.f, b3 = 0.f;
    #pragma unroll 8
    for (int k = h * 128; k < h * 128 + 128; k += 2) {
        b0 = fmaf(aggn[k],     s2wl[k * NC + p],       b0);
        b1 = fmaf(orgn[k],     s2wr[k * NC + p],       b1);
        b2 = fmaf(aggn[k + 1], s2wl[(k + 1) * NC + p], b2);
        b3 = fmaf(orgn[k + 1], s2wr[(k + 1) * NC + p], b3);
    }
    red[t] = (b0 + b1) + (b2 + b3);
    __syncthreads();
    if (t < 128) sm[p] = red[t] + red[t + 128] + s2b[p];
    __syncthreads();
    if (t < 128) red[t] = sm[t];
    __syncthreads();
    for (int s = 64; s > 0; s >>= 1) { if (t < s) red[t] = fmaxf(red[t], red[t + s]); __syncthreads(); }
    float mx = red[0];
    __syncthreads();
    float e = 0.f;
    if (t < 128) { e = expf(sm[t] - mx); red[t] = e; } else { red[t] = 0.f; }
    __syncthreads();
    for (int s = 64; s > 0; s >>= 1) { if (t < s) red[t] += red[t + s]; __syncthreads(); }
    float denom = red[0];
    float q = e / denom;
    if (t < 128) {
        s_soft[n * NC + t] = q;
        s_softT[t * 256 + n] = q;
    }
    float ev = (t < 128) ? -q * logf(q + 1e-15f) : 0.f;
    float esum = block_sum_256(ev, red4);
    if (t == 0) entp[n] = esum;
}

__global__ __launch_bounds__(256) void row_fused_kernel(
    const float* __restrict__ adj, const float* __restrict__ s_soft,
    const float* __restrict__ s_softT, float* __restrict__ T, float* __restrict__ lpart)
{
    int i = blockIdx.x, j = threadIdx.x;
    __shared__ float si[NC], adjrow[256], tbuf[256], red4[4];
    adjrow[j] = adj[i * 256 + j];
    if (j < NC) si[j] = s_soft[i * NC + j];
    __syncthreads();
    float d0 = 0.f, d1 = 0.f, d2 = 0.f, d3 = 0.f;
    #pragma unroll 8
    for (int k = 0; k < NC; k += 4) {
        d0 = fmaf(si[k + 0], s_softT[(k + 0) * 256 + j], d0);
        d1 = fmaf(si[k + 1], s_softT[(k + 1) * 256 + j], d1);
        d2 = fmaf(si[k + 2], s_softT[(k + 2) * 256 + j], d2);
        d3 = fmaf(si[k + 3], s_softT[(k + 3) * 256 + j], d3);
    }
    float dot = (d0 + d1) + (d2 + d3);
    float dd = adjrow[j] - dot;
    float lsum = block_sum_256(dd * dd, red4);
    if (j == 0) lpart[i] = lsum;
    int p = j & 127, h = j >> 7;
    float a0 = 0.f, a1 = 0.f;
    #pragma unroll 8
    for (int k = h * 128; k < h * 128 + 128; k += 2) {
        a0 = fmaf(adjrow[k],     s_soft[k * NC + p],       a0);
        a1 = fmaf(adjrow[k + 1], s_soft[(k + 1) * NC + p], a1);
    }
    tbuf[j] = a0 + a1;
    __syncthreads();
    if (j < 128) T[i * NC + j] = tbuf[j] + tbuf[j + 128];
}

__global__ __launch_bounds__(256) void cluster_fused_kernel(
    const float* __restrict__ s_softT, const float* __restrict__ T, const float* __restrict__ x1g,
    float* __restrict__ eb_out, float* __restrict__ nodes_out)
{
    int c = blockIdx.x, t = threadIdx.x;
    __shared__ float colc[256], red[256], ap[NC], red4[4];
    colc[t] = s_softT[c * 256 + t];
    __syncthreads();
    int p = t & 127, h = t >> 7;
    float a0 = 0.f, a1 = 0.f;
    #pragma unroll 8
    for (int n = h * 128; n < h * 128 + 128; n += 2) {
        a0 = fmaf(colc[n],     T[n * NC + p],       a0);
        a1 = fmaf(colc[n + 1], T[(n + 1) * NC + p], a1);
    }
    red[t] = a0 + a1;
    __syncthreads();
    if (t < 128) ap[t] = red[t] + red[t + 128];
    __syncthreads();
    if (t < 128) red[t] = ap[t];
    __syncthreads();
    for (int s = 64; s > 0; s >>= 1) { if (t < s) red[t] = fmaxf(red[t], red[t + s]); __syncthreads(); }
    float mx = red[0];
    if (t < 128) eb_out[c * NC + t] = (ap[t] == mx) ? 1.f : 0.f;
    float n0 = tanhf(block_sum_256(colc[t] * x1g[t * 2 + 0], red4));
    float n1 = tanhf(block_sum_256(colc[t] * x1g[t * 2 + 1], red4));
    if (t == 0) { nodes_out[c * 2 + 0] = n0; nodes_out[c * 2 + 1] = n1; }
}

__global__ __launch_bounds__(256) void final_kernel(
    const float* __restrict__ lpart, const float* __restrict__ entp,
    const float* __restrict__ eb, const float* __restrict__ nodes,
    const float* __restrict__ wl, const float* __restrict__ wr, const float* __restrict__ b,
    float* __restrict__ out_main, float* __restrict__ out_link, float* __restrict__ out_ent)
{
    int t = threadIdx.x;
    __shared__ float red4[4];
    float ls = block_sum_256(lpart[t], red4);
    if (t == 0) out_link[0] = sqrtf(ls) / (float)(NN * NN);
    float es = block_sum_256(entp[t], red4);
    if (t == 0) out_ent[0] = es / (float)NN;
    if (t < NC) {
        int j = t;
        float i0 = 0.f, i1 = 0.f, a00 = 0.f, a01 = 0.f, a10 = 0.f, a11 = 0.f;
        #pragma unroll 8
        for (int i2 = 0; i2 < NC; i2 += 2) {
            float e0 = eb[i2 * NC + j];
            float e1 = eb[(i2 + 1) * NC + j];
            i0 += e0; i1 += e1;
            a00 = fmaf(e0, nodes[i2 * 2 + 0], a00);
            a01 = fmaf(e0, nodes[i2 * 2 + 1], a01);
            a10 = fmaf(e1, nodes[(i2 + 1) * 2 + 0], a10);
            a11 = fmaf(e1, nodes[(i2 + 1) * 2 + 1], a11);
        }
        float indeg = i0 + i1;
        float a0 = a00 + a10, a1 = a01 + a11;
        float inv = (indeg > 0.f) ? 1.f / fmaxf(indeg, 1.f) : 0.f;
        float g0 = a0 * inv, g1 = a1 * inv;
        float n0 = nodes[j * 2 + 0], n1 = nodes[j * 2 + 1];
        out_main[j * 2 + 0] = g0 * wl[0] + g1 * wl[2] + b[0] + n0 * wr[0] + n1 * wr[2];
        out_main[j * 2 + 1] = g0 * wl[1] + g1 * wl[3] + b[1] + n0 * wr[1] + n1 * wr[3];
    }
}

extern "C" void kernel_launch(void* const* d_in, const int* in_sizes, int n_in,
                              void* d_out, int out_size, void* d_ws, size_t ws_size,
                              hipStream_t stream)
{
    const float* input = (const float*)d_in[0];
    const int* eidx = (const int*)d_in[1];
    const int* src = eidx;
    const int* dst = eidx + NE;
    const float* w1 = (const float*)d_in[2];  const float* b1 = (const float*)d_in[3];
    const float* w2 = (const float*)d_in[4];  const float* b2 = (const float*)d_in[5];
    const float* w3 = (const float*)d_in[6];  const float* b3 = (const float*)d_in[7];
    const float* w4 = (const float*)d_in[8];  const float* b4 = (const float*)d_in[9];
    const float* w5 = (const float*)d_in[10]; const float* b5 = (const float*)d_in[11];
    const float* s1_wl = (const float*)d_in[12]; const float* s1_wr = (const float*)d_in[13];
    const float* s1_b  = (const float*)d_in[14];
    const float* s2_wl = (const float*)d_in[15]; const float* s2_wr = (const float*)d_in[16];
    const float* s2_b  = (const float*)d_in[17];
    const float* s3_wl = (const float*)d_in[18]; const float* s3_wr = (const float*)d_in[19];
    const float* s3_b  = (const float*)d_in[20];

    float* ws = (float*)d_ws;
    unsigned short* c1 = (unsigned short*)(ws);
    unsigned short* c2 = (unsigned short*)(ws + 1048576);
    unsigned short* c3 = (unsigned short*)(ws);
    unsigned short* c4 = (unsigned short*)(ws + 1048576);
    float* P5  = ws;                       // 4*256*32*32 f32, c3 dead by then
    float* ORG = ws + 1179648;
    unsigned short* f2 = (unsigned short*)(ws + 1573888);
    unsigned short* f3 = (unsigned short*)(ws + 1583104);
    unsigned short* f4 = (unsigned short*)(ws + 1619968);
    unsigned short* f5 = (unsigned short*)(ws + 1767424);
    float* adj     = ws + 2062336;
    float* adjT    = ws + 2127872;
    float* s_soft  = ws + 2193408;
    float* T       = ws + 2226176;
    float* x1g     = ws + 2258944;
    float* lpart   = ws + 2259456;
    float* entp    = ws + 2259712;
    float* s_softT = ws + 2259968;   // 128*256

    float* fout = (float*)d_out;
    float* out_main  = fout;
    float* out_link  = fout + 256;
    float* out_ent   = fout + 257;
    float* out_nodes = fout + 258;
    float* out_eb    = fout + 514;

    mega1_kernel<<<2781, 256, 0, stream>>>(input, w1, b1, c1, w2, w3, w4, w5,
                                           f2, f3, f4, f5, src, dst, adj, adjT);
    conv_mfma<32,  64, 256, 64, 1, 128><<<dim3(16, 64, 1), 128, 0, stream>>>(c1, f2, b2, c2);
    conv_mfma<64, 128, 128, 64, 1, 128><<<dim3(8, 32, 2),  128, 0, stream>>>(c2, f3, b3, c3);
    conv_mfma<128, 256, 64, 32, 1, 128><<<dim3(4, 16, 8),  128, 0, stream>>>(c3, f4, b4, c4);
    conv_mfma<256, 256, 32, 32, 4, 128><<<dim3(2, 8, 32),  128, 0, stream>>>(c4, f5, b5, P5);
    finalize_pool<256, 16, 4><<<256, 256, 0, stream>>>(P5, b5, ORG);

    node_fused_kernel<<<256, 256, 0, stream>>>(adjT, ORG, s1_wl, s1_wr, s1_b,
                                               s2_wl, s2_wr, s2_b, s_soft, s_softT, x1g, entp);
    row_fused_kernel<<<256, 256, 0, stream>>>(adj, s_soft, s_softT, T, lpart);
    cluster_fused_kernel<<<128, 256, 0, stream>>>(s_softT, T, x1g, out_eb, out_nodes);
    final_kernel<<<1, 256, 0, stream>>>(lpart, entp, out_eb, out_nodes,
                                        s3_wl, s3_wr, s3_b, out_main, out_link, out_ent);
}